// Round 4
// baseline (378.425 us; speedup 1.0000x reference)
//
#include <hip/hip_runtime.h>

// B=2, S=2048, D=2048, H=16, KV=8, HD=128, N_REP=2.
// I/O: fp32. Compute: bf16 MFMA, fp32 accum.
//
// Pipeline:
//   0. cvt x fp32 -> bf16 (xb)
//   1. wtrans: Wq/Wk/Wv -> WqkvT [4096 n][2048 k], Wo -> WoT  (one launch)
//   2. gemm256: QKV = xb @ WqkvT          (256x256 8-phase counted-vmcnt)
//   3. rope (Q and K parts, one launch)
//   4. transpose V part per-batch -> Vt[b][kv*128+hd][s]
//   5. flash v4: work-stealing, 4-wave blocks (GQA pair shares K/V staging),
//      single-buffer K/V + T14 register prefetch, 40.5 KB LDS -> 3 blocks/CU,
//      grid 768, ones-MFMA row sums, max-free softmax
//   6. gemm256: out = Ab @ WoT -> d_out (fp32)

typedef __bf16 bf16;
typedef __bf16 bf16x4 __attribute__((ext_vector_type(4)));
typedef __bf16 bf16x8 __attribute__((ext_vector_type(8)));
typedef float floatx4 __attribute__((ext_vector_type(4)));

#define AS1(p) ((const __attribute__((address_space(1))) void*)(p))
#define AS3(p) ((__attribute__((address_space(3))) void*)(p))

__device__ __forceinline__ void load16(const void* g, void* l) {
  __builtin_amdgcn_global_load_lds(AS1(g), AS3(l), 16, 0, 0);
}

__device__ __forceinline__ void phase_barrier() {
  asm volatile("" ::: "memory");
  __builtin_amdgcn_sched_barrier(0);
  __builtin_amdgcn_s_barrier();
  __builtin_amdgcn_sched_barrier(0);
  asm volatile("" ::: "memory");
}

// ---------------- fp32 -> bf16 convert ----------------
__global__ __launch_bounds__(256) void cvt_kernel(const float* __restrict__ in,
                                                  bf16* __restrict__ out, int n4) {
  int i = blockIdx.x * blockDim.x + threadIdx.x;
  if (i >= n4) return;
  float4 v = ((const float4*)in)[i];
  bf16x4 o = {(bf16)v.x, (bf16)v.y, (bf16)v.z, (bf16)v.w};
  ((bf16x4*)out)[i] = o;
}

// ---------------- all 4 weight transposes in one launch ----------------
// out[c*2048 + r] = (bf16)W[r*N + c]; rows always 2048.
__global__ __launch_bounds__(256) void wtrans_kernel(
    const float* __restrict__ Wq, const float* __restrict__ Wk,
    const float* __restrict__ Wv, const float* __restrict__ Wo,
    bf16* __restrict__ WqkvT, bf16* __restrict__ WoT) {
  __shared__ float tile[32][33];
  const int wid = blockIdx.z;
  const float* src = wid == 0 ? Wq : wid == 1 ? Wk : wid == 2 ? Wv : Wo;
  bf16* dst = wid == 0 ? WqkvT
            : wid == 1 ? WqkvT + 2048ull * 2048
            : wid == 2 ? WqkvT + 3072ull * 2048
                       : WoT;
  const int ncols = (wid == 1 || wid == 2) ? 1024 : 2048;
  const int c0 = blockIdx.x * 32, r0 = blockIdx.y * 32;
  if (c0 >= ncols) return;
  const int tx = threadIdx.x & 31, ty = threadIdx.x >> 5;  // 32 x 8
#pragma unroll
  for (int i = 0; i < 4; i++) {
    int ri = ty + i * 8;
    tile[ri][tx] = src[(long)(r0 + ri) * ncols + c0 + tx];
  }
  __syncthreads();
#pragma unroll
  for (int i = 0; i < 4; i++) {
    int ci = ty + i * 8;
    dst[(long)(c0 + ci) * 2048 + r0 + tx] = (bf16)tile[tx][ci];
  }
}

// ---------------- bf16 tiled transpose (for V) ----------------
__global__ __launch_bounds__(256) void transpose_bf16(
    const bf16* __restrict__ in, bf16* __restrict__ out,
    int ldi, int ldo, long ibs, long obs) {
  __shared__ bf16 tile[32][33];
  const long ib = ibs * blockIdx.z, ob = obs * blockIdx.z;
  const int c0 = blockIdx.x * 32, r0 = blockIdx.y * 32;
  const int tx = threadIdx.x & 31, ty = threadIdx.x >> 5;
#pragma unroll
  for (int i = 0; i < 4; i++) {
    int ri = ty + i * 8;
    tile[ri][tx] = in[ib + (long)(r0 + ri) * ldi + c0 + tx];
  }
  __syncthreads();
#pragma unroll
  for (int i = 0; i < 4; i++) {
    int ci = ty + i * 8;
    out[ob + (long)(c0 + ci) * ldo + r0 + tx] = tile[tx][ci];
  }
}

// ---------------- GEMM 256x256, 8-phase: C[M,N] = A[M,K] * Bt[N,K]^T ----------------
// 512 threads = 8 waves (wm = wave>>2 in {0,1}, wn = wave&3 in {0..3}).
// Per-wave output 128x64 = acc[8][4] 16x16 frags.
// LDS per buffer (64KB): A [2 half][8 rg][2 kh][16 r][32 k bf16], B same at +32KB.
// Subtile block = 1024B; swizzle: byte ^= ((byte>>9)&1)<<5 (rows 8-15 flip 32B).
// Requires M%256==0, N%256==0, K%128==0.
template <typename CT>
__global__ __launch_bounds__(512, 2) void gemm256(
    const bf16* __restrict__ A, const bf16* __restrict__ Bt, CT* __restrict__ C,
    int M, int N, int K) {
  __shared__ __align__(1024) char smem[131072];
  const int tid = threadIdx.x;
  const int wave = tid >> 6, lane = tid & 63;
  const int quad = lane >> 4, l16 = lane & 15;
  const int wm = wave >> 2, wn = wave & 3;
  const int m0 = blockIdx.y * 256, n0 = blockIdx.x * 256;

  // staging: per load-instr, wave w writes 1024B block (l*8+w); lane writes 16B
  // at linear byte lane*16; global source is inverse-swizzled.
  const int srow = (wave >> 1) * 16 + (lane >> 2);  // row within 64-row load region
  const int skcol = (wave & 1) * 32 + (((lane & 3) * 8) ^ ((lane & 32) ? 16 : 0));
  const int sblk = wave * 1024;

  // fragment-read offsets (swizzled)
  const int qoff = (quad * 16) ^ ((l16 & 8) << 2);
  const int aoff = wm * 16384 + l16 * 64 + qoff;
  const int boff = 32768 + (wn >> 1) * 16384 + (wn & 1) * 8192 + l16 * 64 + qoff;

  auto stageA = [&](int kt, int h, int buf) {
    const bf16* g = A + (size_t)(m0 + h * 128 + srow) * K + kt * 64 + skcol;
    char* d = smem + buf * 65536 + h * 16384 + sblk;
    load16(g, d);
    load16(g + (size_t)64 * K, d + 8192);
  };
  auto stageB = [&](int kt, int h, int buf) {
    const bf16* g = Bt + (size_t)(n0 + h * 128 + srow) * K + kt * 64 + skcol;
    char* d = smem + buf * 65536 + 32768 + h * 16384 + sblk;
    load16(g, d);
    load16(g + (size_t)64 * K, d + 8192);
  };
  auto rdA = [&](int buf, int fr, int ks) {
    return *(const bf16x8*)(smem + buf * 65536 + aoff + (fr * 2 + ks) * 1024);
  };
  auto rdB = [&](int buf, int fc, int ks) {
    return *(const bf16x8*)(smem + buf * 65536 + boff + (fc * 2 + ks) * 1024);
  };

  floatx4 acc[8][4] = {};

  const int nkt = K >> 6;
  const int niter = nkt >> 1;

  // prologue: tile0 -> buf0 (8 loads), tile1 B halves -> buf1 (4 loads)
  stageB(0, 0, 0); stageB(0, 1, 0);
  stageA(0, 0, 0); stageA(0, 1, 0);
  stageB(1, 0, 1); stageB(1, 1, 1);
  asm volatile("s_waitcnt vmcnt(4)" ::: "memory");
  phase_barrier();

  for (int it = 0; it < niter; ++it) {
    const int T = 2 * it;
    const bool morek = (it < niter - 1);
#pragma unroll
    for (int c = 0; c < 2; ++c) {
      const int buf = c;
      const int tA = T + 1 + c;   // A halves of this tile -> buf^1 (phases 1,2)
      const int tB = T + 2 + c;   // B halves of this tile -> buf   (phases 3,4)
      const bool stA = (c == 0) || morek;

      bf16x8 a[4][2], b01[2][2], b23[2][2];

      // ---- phase 1: Q(0,0) = A rows 0-3 x B cols 0-1 ----
#pragma unroll
      for (int fr = 0; fr < 4; ++fr)
#pragma unroll
        for (int ks = 0; ks < 2; ++ks) a[fr][ks] = rdA(buf, fr, ks);
#pragma unroll
      for (int fc = 0; fc < 2; ++fc)
#pragma unroll
        for (int ks = 0; ks < 2; ++ks) b01[fc][ks] = rdB(buf, fc, ks);
      if (stA) stageA(tA, 0, buf ^ 1);
      phase_barrier();
      __builtin_amdgcn_s_setprio(1);
#pragma unroll
      for (int ks = 0; ks < 2; ++ks)
#pragma unroll
        for (int fr = 0; fr < 4; ++fr)
#pragma unroll
          for (int fc = 0; fc < 2; ++fc)
            acc[fr][fc] = __builtin_amdgcn_mfma_f32_16x16x32_bf16(
                a[fr][ks], b01[fc][ks], acc[fr][fc], 0, 0, 0);
      __builtin_amdgcn_s_setprio(0);
      phase_barrier();

      // ---- phase 2: Q(0,1) = A rows 0-3 x B cols 2-3 ----
#pragma unroll
      for (int fc = 0; fc < 2; ++fc)
#pragma unroll
        for (int ks = 0; ks < 2; ++ks) b23[fc][ks] = rdB(buf, 2 + fc, ks);
      if (stA) stageA(tA, 1, buf ^ 1);
      phase_barrier();
      __builtin_amdgcn_s_setprio(1);
#pragma unroll
      for (int ks = 0; ks < 2; ++ks)
#pragma unroll
        for (int fr = 0; fr < 4; ++fr)
#pragma unroll
          for (int fc = 0; fc < 2; ++fc)
            acc[fr][2 + fc] = __builtin_amdgcn_mfma_f32_16x16x32_bf16(
                a[fr][ks], b23[fc][ks], acc[fr][2 + fc], 0, 0, 0);
      __builtin_amdgcn_s_setprio(0);
      phase_barrier();

      // ---- phase 3: Q(1,1) = A rows 4-7 x B cols 2-3 ----
#pragma unroll
      for (int fr = 0; fr < 4; ++fr)
#pragma unroll
        for (int ks = 0; ks < 2; ++ks) a[fr][ks] = rdA(buf, 4 + fr, ks);
      if (morek) stageB(tB, 0, buf);
      phase_barrier();
      __builtin_amdgcn_s_setprio(1);
#pragma unroll
      for (int ks = 0; ks < 2; ++ks)
#pragma unroll
        for (int fr = 0; fr < 4; ++fr)
#pragma unroll
          for (int fc = 0; fc < 2; ++fc)
            acc[4 + fr][2 + fc] = __builtin_amdgcn_mfma_f32_16x16x32_bf16(
                a[fr][ks], b23[fc][ks], acc[4 + fr][2 + fc], 0, 0, 0);
      __builtin_amdgcn_s_setprio(0);
      phase_barrier();

      // ---- phase 4: Q(1,0) = A rows 4-7 x B cols 0-1 ----
      if (morek) stageB(tB, 1, buf);
      if (morek)
        asm volatile("s_waitcnt vmcnt(4)" ::: "memory");
      else
        asm volatile("s_waitcnt vmcnt(0)" ::: "memory");
      phase_barrier();
      __builtin_amdgcn_s_setprio(1);
#pragma unroll
      for (int ks = 0; ks < 2; ++ks)
#pragma unroll
        for (int fr = 0; fr < 4; ++fr)
#pragma unroll
          for (int fc = 0; fc < 2; ++fc)
            acc[4 + fr][fc] = __builtin_amdgcn_mfma_f32_16x16x32_bf16(
                a[fr][ks], b01[fc][ks], acc[4 + fr][fc], 0, 0, 0);
      __builtin_amdgcn_s_setprio(0);
      phase_barrier();
    }
  }

  // epilogue
#pragma unroll
  for (int fr = 0; fr < 8; ++fr)
#pragma unroll
    for (int fc = 0; fc < 4; ++fc)
#pragma unroll
      for (int r = 0; r < 4; ++r) {
        int row = m0 + wm * 128 + fr * 16 + quad * 4 + r;
        int col = n0 + wn * 64 + fc * 16 + l16;
        C[(size_t)row * N + col] = (CT)acc[fr][fc][r];
      }
}

// ---------------- RoPE, Q part + K part in one launch ----------------
__global__ void rope_kernel(bf16* __restrict__ QKV, const float* __restrict__ cosb,
                            const float* __restrict__ sinb) {
  int idx = blockIdx.x * blockDim.x + threadIdx.x;
  if (idx >= 6291456) return;
  int nh, nhs, offc;
  if (idx < 4194304) { nh = 16; nhs = 4; offc = 0; }
  else { idx -= 4194304; nh = 8; nhs = 3; offc = 2048; }
  int d = idx & 63;
  int rest = idx >> 6;
  int hh = rest & (nh - 1);
  int bs = rest >> nhs;  // b*2048 + s
  int s = bs & 2047;
  size_t base = (size_t)bs * 4096 + offc + hh * 128;
  float c0 = cosb[s * 128 + d];
  float c1 = cosb[s * 128 + d + 64];
  float s0 = sinb[s * 128 + d];
  float s1 = sinb[s * 128 + d + 64];
  float x0 = (float)QKV[base + d];
  float x1 = (float)QKV[base + d + 64];
  QKV[base + d] = (bf16)(x0 * c0 - x1 * s0);
  QKV[base + d + 64] = (bf16)(x1 * c1 + x0 * s1);
}

// ---------------- Flash v4: work-stealing, GQA-paired, T14 single-buf K/V ----------------
// Items: w in [0,1024): qt = 63 - (w>>4) (longest-first), b = (w>>3)&1, kvh = w&7.
// Block = 256 threads (4 waves). Wave w: h = 2*kvh + (w>>1), q-rows
// [qt*32 + (w&1)*16, +16). K-tile = 64 keys, nkt = qt/2 + 1.
// LDS (40.5 KB -> 3 blocks/CU, grid 768):
//      K [64 key][128 hd] swz&15   16 KB @ 0     (also Q staging)
//      V [128 hd][64 key] swz&7    16 KB @ 16K
//      P [wave][16 q][64 k] swz&7   8 KB @ 32K
// T14: tile kt+1 prefetched into registers (inline-asm global_load_dwordx4)
// before compute of kt; after barrier A (all waves done reading kt):
// vmcnt(0) -> ds_write_b128 -> lgkmcnt(0) -> barrier B. 2 barriers/tile.

template <bool MASK>
__device__ __forceinline__ void attn_step32(
    const bf16* Kc, const bf16* Vc, bf16* Pw, const bf16x8 (&aq)[4],
    const bf16x8& ones, floatx4 (&oacc)[8], floatx4& lacc,
    int k0, int q0w, int l16, int quad) {
  floatx4 sacc[4] = {};
  __builtin_amdgcn_s_setprio(1);
#pragma unroll
  for (int ks = 0; ks < 4; ks++)
#pragma unroll
    for (int j = 0; j < 4; j++) {
      int row = j * 16 + l16;
      bf16x8 bk = *(const bf16x8*)(Kc + row * 128 + (((ks * 4 + quad) ^ (row & 15)) * 8));
      sacc[j] = __builtin_amdgcn_mfma_f32_16x16x32_bf16(aq[ks], bk, sacc[j], 0, 0, 0);
    }
  __builtin_amdgcn_s_setprio(0);
  const float C = 0.12752188659023044f;  // (1/sqrt(128)) * log2(e)
#pragma unroll
  for (int r = 0; r < 4; r++) {
    int row = quad * 4 + r;
#pragma unroll
    for (int j = 0; j < 4; j++) {
      float p = exp2f(sacc[j][r] * C);
      if (MASK) {
        int key = k0 + j * 16 + l16;
        if (key > q0w + row) p = 0.f;
      }
      int col = j * 16 + l16;
      Pw[row * 64 + (((col >> 3) ^ (row & 7)) * 8) + (col & 7)] = (bf16)p;
    }
  }
  __builtin_amdgcn_s_setprio(1);
#pragma unroll
  for (int ks = 0; ks < 2; ks++) {
    bf16x8 ap = *(const bf16x8*)(Pw + l16 * 64 + (((ks * 4 + quad) ^ (l16 & 7)) * 8));
    lacc = __builtin_amdgcn_mfma_f32_16x16x32_bf16(ap, ones, lacc, 0, 0, 0);
#pragma unroll
    for (int j = 0; j < 8; j++) {
      int vr = j * 16 + l16;
      bf16x8 bv = *(const bf16x8*)(Vc + vr * 64 + (((ks * 4 + quad) ^ (vr & 7)) * 8));
      oacc[j] = __builtin_amdgcn_mfma_f32_16x16x32_bf16(ap, bv, oacc[j], 0, 0, 0);
    }
  }
  __builtin_amdgcn_s_setprio(0);
}

__global__ __launch_bounds__(256, 3) void flash_kernel(
    const bf16* __restrict__ QKV, const bf16* __restrict__ Vt, bf16* __restrict__ O,
    int* __restrict__ cnt) {
  __shared__ __align__(1024) char smem[40960];
  __shared__ int wsh;
  const int tid = threadIdx.x;
  const int wave = tid >> 6, lane = tid & 63, quad = lane >> 4, l16 = lane & 15;
  const int wbase = tid & ~63;
  const int hloc = wave >> 1, rhalf = wave & 1;
  bf16* Pw = (bf16*)(smem + 32768) + wave * 1024;
  const bf16* Kc = (const bf16*)smem;
  const bf16* Vc = (const bf16*)(smem + 16384);
  bf16x8 ones;
#pragma unroll
  for (int e = 0; e < 8; e++) ones[e] = (bf16)1.0f;

  for (;;) {
    if (tid == 0) wsh = atomicAdd(cnt, 1);
    __syncthreads();  // publish wsh; prior item's LDS use fully done (drains cnts)
    const int w = wsh;
    if (w >= 1024) break;
    const int qt = 63 - (w >> 4);
    const int b = (w >> 3) & 1, kvh = w & 7;
    const int h = kvh * 2 + hloc;
    const int q0 = qt * 32;
    const int nkt = (qt >> 1) + 1;

    // stage Q [2h x 32 q][128 hd] into K region, chunk-swizzled by row&15
#pragma unroll
    for (int u = 0; u < 4; u++) {
      int g = u * 256 + tid;
      int row = g >> 4, cc = g & 15;
      const bf16* gp = QKV + (size_t)(b * 2048 + q0 + (row & 31)) * 4096 +
                       (kvh * 2 + (row >> 5)) * 128 + ((cc ^ (row & 15)) * 8);
      load16(gp, smem + (u * 256 + wbase) * 16);
    }
    asm volatile("s_waitcnt vmcnt(0)" ::: "memory");
    phase_barrier();  // Q visible to all waves (sched-fenced: aq reads can't hoist)
    bf16x8 aq[4];
    {
      int row = hloc * 32 + rhalf * 16 + l16;
#pragma unroll
      for (int ks = 0; ks < 4; ks++)
        aq[ks] = *(const bf16x8*)((const bf16*)smem + row * 128 +
                                  (((ks * 4 + quad) ^ (row & 15)) * 8));
    }
    __syncthreads();  // aq reads complete (lgkm drained) before K0/V0 overwrite Q

    // stage K/V tile 0 directly to LDS (destination free)
#pragma unroll
    for (int u = 0; u < 4; u++) {
      int g = u * 256 + tid;
      int krow = g >> 4, kcc = g & 15;
      const bf16* kp = QKV + (size_t)(b * 2048 + krow) * 4096 + 2048 +
                       kvh * 128 + ((kcc ^ (krow & 15)) * 8);
      load16(kp, smem + (u * 256 + wbase) * 16);
      int vrow = g >> 3, vcc = g & 7;
      const bf16* vp = Vt + (size_t)(b * 1024 + kvh * 128 + vrow) * 2048 +
                       ((vcc ^ (vrow & 7)) * 8);
      load16(vp, smem + 16384 + (u * 256 + wbase) * 16);
    }
    asm volatile("s_waitcnt vmcnt(0)" ::: "memory");
    phase_barrier();  // tile 0 visible; loop invariant established

    floatx4 oacc[8] = {};
    floatx4 lacc = {};
    const int q0w = q0 + rhalf * 16;

    floatx4 kr[4], vr[4];
    for (int kt = 0; kt < nkt; kt++) {
      const bool pf = (kt + 1 < nkt);
      if (pf) {
        // T14 issue-early: prefetch tile kt+1 into registers (asm pins issue here)
#pragma unroll
        for (int u = 0; u < 4; u++) {
          int g = u * 256 + tid;
          int krow = g >> 4, kcc = g & 15;
          const bf16* kp = QKV + (size_t)(b * 2048 + (kt + 1) * 64 + krow) * 4096 +
                           2048 + kvh * 128 + ((kcc ^ (krow & 15)) * 8);
          asm volatile("global_load_dwordx4 %0, %1, off"
                       : "=&v"(kr[u]) : "v"(kp) : "memory");
          int vrow = g >> 3, vcc = g & 7;
          const bf16* vp = Vt + (size_t)(b * 1024 + kvh * 128 + vrow) * 2048 +
                           (kt + 1) * 64 + ((vcc ^ (vrow & 7)) * 8);
          asm volatile("global_load_dwordx4 %0, %1, off"
                       : "=&v"(vr[u]) : "v"(vp) : "memory");
        }
      }
      if (kt == nkt - 1)
        attn_step32<true>(Kc, Vc, Pw, aq, ones, oacc, lacc, kt * 64, q0w, l16, quad);
      else
        attn_step32<false>(Kc, Vc, Pw, aq, ones, oacc, lacc, kt * 64, q0w, l16, quad);
      phase_barrier();  // A: all waves done reading K/V/P for tile kt
      if (pf) {
        asm volatile("s_waitcnt vmcnt(0)" ::: "memory");  // own prefetch arrived
        __builtin_amdgcn_sched_barrier(0);
#pragma unroll
        for (int u = 0; u < 4; u++) {
          *(floatx4*)(smem + (u * 256 + tid) * 16) = kr[u];
          *(floatx4*)(smem + 16384 + (u * 256 + tid) * 16) = vr[u];
        }
        asm volatile("s_waitcnt lgkmcnt(0)" ::: "memory");
        phase_barrier();  // B: tile kt+1 visible to all waves
      }
    }

    // epilogue: O = oacc / rowsum  (lacc has the row sum in every column)
    float rl[4];
#pragma unroll
    for (int r = 0; r < 4; r++) rl[r] = 1.0f / lacc[r];
#pragma unroll
    for (int j = 0; j < 8; j++)
#pragma unroll
      for (int r = 0; r < 4; r++) {
        int s = q0w + quad * 4 + r;
        O[(size_t)(b * 2048 + s) * 2048 + h * 128 + j * 16 + l16] =
            (bf16)(oacc[j][r] * rl[r]);
      }
  }
}

extern "C" void kernel_launch(void* const* d_in, const int* in_sizes, int n_in,
                              void* d_out, int out_size, void* d_ws, size_t ws_size,
                              hipStream_t stream) {
  (void)in_sizes; (void)n_in; (void)out_size; (void)ws_size;
  const float* x    = (const float*)d_in[0];
  const float* cosb = (const float*)d_in[1];
  const float* sinb = (const float*)d_in[2];
  const float* Wq   = (const float*)d_in[3];
  const float* Wk   = (const float*)d_in[4];
  const float* Wv   = (const float*)d_in[5];
  const float* Wo   = (const float*)d_in[6];
  float* out = (float*)d_out;

  char* ws = (char*)d_ws;
  size_t off = 0;
  auto alloc = [&](size_t bytes) { void* p = ws + off; off += bytes; return p; };
  bf16* xb    = (bf16*)alloc(4096ull * 2048 * 2);  // 16 MB
  bf16* WqkvT = (bf16*)alloc(4096ull * 2048 * 2);  // 16 MB  [Wq^T | Wk^T | Wv^T]
  bf16* WoT   = (bf16*)alloc(2048ull * 2048 * 2);  //  8 MB
  bf16* QKV   = (bf16*)alloc(4096ull * 4096 * 2);  // 32 MB  [s][Q 2048 | K 1024 | V 1024]
  bf16* Vtb   = (bf16*)alloc(2048ull * 2048 * 2);  //  8 MB  [b][kv*128+hd][s]
  bf16* Ab    = (bf16*)alloc(4096ull * 2048 * 2);  // 16 MB
  int*  cnt   = (int*)alloc(256);                  // work-steal counter

  // 0. x -> bf16; zero the work counter (stream op, graph-capture safe)
  cvt_kernel<<<8192, 256, 0, stream>>>(x, xb, 2097152);
  hipMemsetAsync(cnt, 0, 256, stream);

  // 1. weight transposes (fp32 -> bf16), one launch
  wtrans_kernel<<<dim3(64, 64, 4), 256, 0, stream>>>(Wq, Wk, Wv, Wo, WqkvT, WoT);

  // 2. fused QKV projection: [4096 s] x [4096 n], 256^2 8-phase
  gemm256<bf16><<<dim3(16, 16), 512, 0, stream>>>(xb, WqkvT, QKV, 4096, 4096, 2048);

  // 3. RoPE on Q and K parts, one launch
  rope_kernel<<<24576, 256, 0, stream>>>(QKV, cosb, sinb);

  // 4. V transpose per batch: [2048 s][1024 c] -> [1024 c][2048 s]
  transpose_bf16<<<dim3(32, 64, 2), 256, 0, stream>>>(
      QKV + 3072, Vtb, 4096, 2048, 2048ll * 4096, 1024ll * 2048);

  // 5. flash attention v4: 3 blocks/CU, T14 single-buffer K/V
  flash_kernel<<<dim3(768, 1, 1), 256, 0, stream>>>(QKV, Vtb, Ab, cnt);

  // 6. output projection -> fp32 out, 256^2 8-phase
  gemm256<float><<<dim3(8, 16), 512, 0, stream>>>(Ab, WoT, out, 4096, 2048, 2048);
}

// Round 5
// 362.123 us; speedup vs baseline: 1.0450x; 1.0450x over previous
//
#include <hip/hip_runtime.h>

// B=2, S=2048, D=2048, H=16, KV=8, HD=128, N_REP=2.
// I/O: fp32. Compute: bf16 MFMA, fp32 accum.
//
// Pipeline:
//   0. cvt x fp32 -> bf16 (xb)
//   1. wtrans: Wq/Wk/Wv -> WqkvT [4096 n][2048 k], Wo -> WoT  (one launch)
//   2. gemm256: QKV = xb @ WqkvT          (256x256 8-phase counted-vmcnt)
//   3. rope (Q and K parts, one launch)
//   4. transpose V part per-batch -> Vt[b][kv*128+hd][s]
//   5. flash v5: v4 structure, prefetch state in NAMED registers (rule-20 fix:
//      no asm-written arrays -> no scratch). 40.5 KB LDS, 3 blocks/CU, grid 768.
//   6. gemm256: out = Ab @ WoT -> d_out (fp32)

typedef __bf16 bf16;
typedef __bf16 bf16x4 __attribute__((ext_vector_type(4)));
typedef __bf16 bf16x8 __attribute__((ext_vector_type(8)));
typedef float floatx4 __attribute__((ext_vector_type(4)));

#define AS1(p) ((const __attribute__((address_space(1))) void*)(p))
#define AS3(p) ((__attribute__((address_space(3))) void*)(p))

__device__ __forceinline__ void load16(const void* g, void* l) {
  __builtin_amdgcn_global_load_lds(AS1(g), AS3(l), 16, 0, 0);
}

__device__ __forceinline__ void phase_barrier() {
  asm volatile("" ::: "memory");
  __builtin_amdgcn_sched_barrier(0);
  __builtin_amdgcn_s_barrier();
  __builtin_amdgcn_sched_barrier(0);
  asm volatile("" ::: "memory");
}

// ---------------- fp32 -> bf16 convert ----------------
__global__ __launch_bounds__(256) void cvt_kernel(const float* __restrict__ in,
                                                  bf16* __restrict__ out, int n4) {
  int i = blockIdx.x * blockDim.x + threadIdx.x;
  if (i >= n4) return;
  float4 v = ((const float4*)in)[i];
  bf16x4 o = {(bf16)v.x, (bf16)v.y, (bf16)v.z, (bf16)v.w};
  ((bf16x4*)out)[i] = o;
}

// ---------------- all 4 weight transposes in one launch ----------------
// out[c*2048 + r] = (bf16)W[r*N + c]; rows always 2048.
__global__ __launch_bounds__(256) void wtrans_kernel(
    const float* __restrict__ Wq, const float* __restrict__ Wk,
    const float* __restrict__ Wv, const float* __restrict__ Wo,
    bf16* __restrict__ WqkvT, bf16* __restrict__ WoT) {
  __shared__ float tile[32][33];
  const int wid = blockIdx.z;
  const float* src = wid == 0 ? Wq : wid == 1 ? Wk : wid == 2 ? Wv : Wo;
  bf16* dst = wid == 0 ? WqkvT
            : wid == 1 ? WqkvT + 2048ull * 2048
            : wid == 2 ? WqkvT + 3072ull * 2048
                       : WoT;
  const int ncols = (wid == 1 || wid == 2) ? 1024 : 2048;
  const int c0 = blockIdx.x * 32, r0 = blockIdx.y * 32;
  if (c0 >= ncols) return;
  const int tx = threadIdx.x & 31, ty = threadIdx.x >> 5;  // 32 x 8
#pragma unroll
  for (int i = 0; i < 4; i++) {
    int ri = ty + i * 8;
    tile[ri][tx] = src[(long)(r0 + ri) * ncols + c0 + tx];
  }
  __syncthreads();
#pragma unroll
  for (int i = 0; i < 4; i++) {
    int ci = ty + i * 8;
    dst[(long)(c0 + ci) * 2048 + r0 + tx] = (bf16)tile[tx][ci];
  }
}

// ---------------- bf16 tiled transpose (for V) ----------------
__global__ __launch_bounds__(256) void transpose_bf16(
    const bf16* __restrict__ in, bf16* __restrict__ out,
    int ldi, int ldo, long ibs, long obs) {
  __shared__ bf16 tile[32][33];
  const long ib = ibs * blockIdx.z, ob = obs * blockIdx.z;
  const int c0 = blockIdx.x * 32, r0 = blockIdx.y * 32;
  const int tx = threadIdx.x & 31, ty = threadIdx.x >> 5;
#pragma unroll
  for (int i = 0; i < 4; i++) {
    int ri = ty + i * 8;
    tile[ri][tx] = in[ib + (long)(r0 + ri) * ldi + c0 + tx];
  }
  __syncthreads();
#pragma unroll
  for (int i = 0; i < 4; i++) {
    int ci = ty + i * 8;
    out[ob + (long)(c0 + ci) * ldo + r0 + tx] = tile[tx][ci];
  }
}

// ---------------- GEMM 256x256, 8-phase: C[M,N] = A[M,K] * Bt[N,K]^T ----------------
// 512 threads = 8 waves (wm = wave>>2 in {0,1}, wn = wave&3 in {0..3}).
// Per-wave output 128x64 = acc[8][4] 16x16 frags.
// LDS per buffer (64KB): A [2 half][8 rg][2 kh][16 r][32 k bf16], B same at +32KB.
// Subtile block = 1024B; swizzle: byte ^= ((byte>>9)&1)<<5 (rows 8-15 flip 32B).
// Requires M%256==0, N%256==0, K%128==0.
template <typename CT>
__global__ __launch_bounds__(512, 2) void gemm256(
    const bf16* __restrict__ A, const bf16* __restrict__ Bt, CT* __restrict__ C,
    int M, int N, int K) {
  __shared__ __align__(1024) char smem[131072];
  const int tid = threadIdx.x;
  const int wave = tid >> 6, lane = tid & 63;
  const int quad = lane >> 4, l16 = lane & 15;
  const int wm = wave >> 2, wn = wave & 3;
  const int m0 = blockIdx.y * 256, n0 = blockIdx.x * 256;

  // staging: per load-instr, wave w writes 1024B block (l*8+w); lane writes 16B
  // at linear byte lane*16; global source is inverse-swizzled.
  const int srow = (wave >> 1) * 16 + (lane >> 2);  // row within 64-row load region
  const int skcol = (wave & 1) * 32 + (((lane & 3) * 8) ^ ((lane & 32) ? 16 : 0));
  const int sblk = wave * 1024;

  // fragment-read offsets (swizzled)
  const int qoff = (quad * 16) ^ ((l16 & 8) << 2);
  const int aoff = wm * 16384 + l16 * 64 + qoff;
  const int boff = 32768 + (wn >> 1) * 16384 + (wn & 1) * 8192 + l16 * 64 + qoff;

  auto stageA = [&](int kt, int h, int buf) {
    const bf16* g = A + (size_t)(m0 + h * 128 + srow) * K + kt * 64 + skcol;
    char* d = smem + buf * 65536 + h * 16384 + sblk;
    load16(g, d);
    load16(g + (size_t)64 * K, d + 8192);
  };
  auto stageB = [&](int kt, int h, int buf) {
    const bf16* g = Bt + (size_t)(n0 + h * 128 + srow) * K + kt * 64 + skcol;
    char* d = smem + buf * 65536 + 32768 + h * 16384 + sblk;
    load16(g, d);
    load16(g + (size_t)64 * K, d + 8192);
  };
  auto rdA = [&](int buf, int fr, int ks) {
    return *(const bf16x8*)(smem + buf * 65536 + aoff + (fr * 2 + ks) * 1024);
  };
  auto rdB = [&](int buf, int fc, int ks) {
    return *(const bf16x8*)(smem + buf * 65536 + boff + (fc * 2 + ks) * 1024);
  };

  floatx4 acc[8][4] = {};

  const int nkt = K >> 6;
  const int niter = nkt >> 1;

  // prologue: tile0 -> buf0 (8 loads), tile1 B halves -> buf1 (4 loads)
  stageB(0, 0, 0); stageB(0, 1, 0);
  stageA(0, 0, 0); stageA(0, 1, 0);
  stageB(1, 0, 1); stageB(1, 1, 1);
  asm volatile("s_waitcnt vmcnt(4)" ::: "memory");
  phase_barrier();

  for (int it = 0; it < niter; ++it) {
    const int T = 2 * it;
    const bool morek = (it < niter - 1);
#pragma unroll
    for (int c = 0; c < 2; ++c) {
      const int buf = c;
      const int tA = T + 1 + c;   // A halves of this tile -> buf^1 (phases 1,2)
      const int tB = T + 2 + c;   // B halves of this tile -> buf   (phases 3,4)
      const bool stA = (c == 0) || morek;

      bf16x8 a[4][2], b01[2][2], b23[2][2];

      // ---- phase 1: Q(0,0) = A rows 0-3 x B cols 0-1 ----
#pragma unroll
      for (int fr = 0; fr < 4; ++fr)
#pragma unroll
        for (int ks = 0; ks < 2; ++ks) a[fr][ks] = rdA(buf, fr, ks);
#pragma unroll
      for (int fc = 0; fc < 2; ++fc)
#pragma unroll
        for (int ks = 0; ks < 2; ++ks) b01[fc][ks] = rdB(buf, fc, ks);
      if (stA) stageA(tA, 0, buf ^ 1);
      phase_barrier();
      __builtin_amdgcn_s_setprio(1);
#pragma unroll
      for (int ks = 0; ks < 2; ++ks)
#pragma unroll
        for (int fr = 0; fr < 4; ++fr)
#pragma unroll
          for (int fc = 0; fc < 2; ++fc)
            acc[fr][fc] = __builtin_amdgcn_mfma_f32_16x16x32_bf16(
                a[fr][ks], b01[fc][ks], acc[fr][fc], 0, 0, 0);
      __builtin_amdgcn_s_setprio(0);
      phase_barrier();

      // ---- phase 2: Q(0,1) = A rows 0-3 x B cols 2-3 ----
#pragma unroll
      for (int fc = 0; fc < 2; ++fc)
#pragma unroll
        for (int ks = 0; ks < 2; ++ks) b23[fc][ks] = rdB(buf, 2 + fc, ks);
      if (stA) stageA(tA, 1, buf ^ 1);
      phase_barrier();
      __builtin_amdgcn_s_setprio(1);
#pragma unroll
      for (int ks = 0; ks < 2; ++ks)
#pragma unroll
        for (int fr = 0; fr < 4; ++fr)
#pragma unroll
          for (int fc = 0; fc < 2; ++fc)
            acc[fr][2 + fc] = __builtin_amdgcn_mfma_f32_16x16x32_bf16(
                a[fr][ks], b23[fc][ks], acc[fr][2 + fc], 0, 0, 0);
      __builtin_amdgcn_s_setprio(0);
      phase_barrier();

      // ---- phase 3: Q(1,1) = A rows 4-7 x B cols 2-3 ----
#pragma unroll
      for (int fr = 0; fr < 4; ++fr)
#pragma unroll
        for (int ks = 0; ks < 2; ++ks) a[fr][ks] = rdA(buf, 4 + fr, ks);
      if (morek) stageB(tB, 0, buf);
      phase_barrier();
      __builtin_amdgcn_s_setprio(1);
#pragma unroll
      for (int ks = 0; ks < 2; ++ks)
#pragma unroll
        for (int fr = 0; fr < 4; ++fr)
#pragma unroll
          for (int fc = 0; fc < 2; ++fc)
            acc[4 + fr][2 + fc] = __builtin_amdgcn_mfma_f32_16x16x32_bf16(
                a[fr][ks], b23[fc][ks], acc[4 + fr][2 + fc], 0, 0, 0);
      __builtin_amdgcn_s_setprio(0);
      phase_barrier();

      // ---- phase 4: Q(1,0) = A rows 4-7 x B cols 0-1 ----
      if (morek) stageB(tB, 1, buf);
      if (morek)
        asm volatile("s_waitcnt vmcnt(4)" ::: "memory");
      else
        asm volatile("s_waitcnt vmcnt(0)" ::: "memory");
      phase_barrier();
      __builtin_amdgcn_s_setprio(1);
#pragma unroll
      for (int ks = 0; ks < 2; ++ks)
#pragma unroll
        for (int fr = 0; fr < 4; ++fr)
#pragma unroll
          for (int fc = 0; fc < 2; ++fc)
            acc[4 + fr][fc] = __builtin_amdgcn_mfma_f32_16x16x32_bf16(
                a[fr][ks], b01[fc][ks], acc[4 + fr][fc], 0, 0, 0);
      __builtin_amdgcn_s_setprio(0);
      phase_barrier();
    }
  }

  // epilogue
#pragma unroll
  for (int fr = 0; fr < 8; ++fr)
#pragma unroll
    for (int fc = 0; fc < 4; ++fc)
#pragma unroll
      for (int r = 0; r < 4; ++r) {
        int row = m0 + wm * 128 + fr * 16 + quad * 4 + r;
        int col = n0 + wn * 64 + fc * 16 + l16;
        C[(size_t)row * N + col] = (CT)acc[fr][fc][r];
      }
}

// ---------------- RoPE, Q part + K part in one launch ----------------
__global__ void rope_kernel(bf16* __restrict__ QKV, const float* __restrict__ cosb,
                            const float* __restrict__ sinb) {
  int idx = blockIdx.x * blockDim.x + threadIdx.x;
  if (idx >= 6291456) return;
  int nh, nhs, offc;
  if (idx < 4194304) { nh = 16; nhs = 4; offc = 0; }
  else { idx -= 4194304; nh = 8; nhs = 3; offc = 2048; }
  int d = idx & 63;
  int rest = idx >> 6;
  int hh = rest & (nh - 1);
  int bs = rest >> nhs;  // b*2048 + s
  int s = bs & 2047;
  size_t base = (size_t)bs * 4096 + offc + hh * 128;
  float c0 = cosb[s * 128 + d];
  float c1 = cosb[s * 128 + d + 64];
  float s0 = sinb[s * 128 + d];
  float s1 = sinb[s * 128 + d + 64];
  float x0 = (float)QKV[base + d];
  float x1 = (float)QKV[base + d + 64];
  QKV[base + d] = (bf16)(x0 * c0 - x1 * s0);
  QKV[base + d + 64] = (bf16)(x1 * c1 + x0 * s1);
}

// ---------------- Flash v5: v4 structure, named-register T14 prefetch ----------------
// Items: w in [0,1024): qt = 63 - (w>>4) (longest-first), b = (w>>3)&1, kvh = w&7.
// Block = 256 threads (4 waves). Wave w: h = 2*kvh + (w>>1), q-rows
// [qt*32 + (w&1)*16, +16). K-tile = 64 keys, nkt = qt/2 + 1.
// LDS (40.5 KB -> 3 blocks/CU, grid 768):
//      K [64 key][128 hd] swz&15   16 KB @ 0     (also Q staging)
//      V [128 hd][64 key] swz&7    16 KB @ 16K
//      P [wave][16 q][64 k] swz&7   8 KB @ 32K
// T14: tile kt+1 prefetched into 8 NAMED floatx4 regs (kr0..3, vr0..3) via asm
// global_load_dwordx4 (no arrays -> no scratch, rule 20). After barrier A:
// vmcnt(0) -> 8x ds_write_b128 -> lgkmcnt(0) -> barrier B.

template <bool MASK>
__device__ __forceinline__ void attn_step32(
    const bf16* Kc, const bf16* Vc, bf16* Pw, const bf16x8 (&aq)[4],
    const bf16x8& ones, floatx4 (&oacc)[8], floatx4& lacc,
    int k0, int q0w, int l16, int quad) {
  floatx4 sacc[4] = {};
  __builtin_amdgcn_s_setprio(1);
#pragma unroll
  for (int ks = 0; ks < 4; ks++)
#pragma unroll
    for (int j = 0; j < 4; j++) {
      int row = j * 16 + l16;
      bf16x8 bk = *(const bf16x8*)(Kc + row * 128 + (((ks * 4 + quad) ^ (row & 15)) * 8));
      sacc[j] = __builtin_amdgcn_mfma_f32_16x16x32_bf16(aq[ks], bk, sacc[j], 0, 0, 0);
    }
  __builtin_amdgcn_s_setprio(0);
  const float C = 0.12752188659023044f;  // (1/sqrt(128)) * log2(e)
#pragma unroll
  for (int r = 0; r < 4; r++) {
    int row = quad * 4 + r;
#pragma unroll
    for (int j = 0; j < 4; j++) {
      float p = exp2f(sacc[j][r] * C);
      if (MASK) {
        int key = k0 + j * 16 + l16;
        if (key > q0w + row) p = 0.f;
      }
      int col = j * 16 + l16;
      Pw[row * 64 + (((col >> 3) ^ (row & 7)) * 8) + (col & 7)] = (bf16)p;
    }
  }
  __builtin_amdgcn_s_setprio(1);
#pragma unroll
  for (int ks = 0; ks < 2; ks++) {
    bf16x8 ap = *(const bf16x8*)(Pw + l16 * 64 + (((ks * 4 + quad) ^ (l16 & 7)) * 8));
    lacc = __builtin_amdgcn_mfma_f32_16x16x32_bf16(ap, ones, lacc, 0, 0, 0);
#pragma unroll
    for (int j = 0; j < 8; j++) {
      int vr = j * 16 + l16;
      bf16x8 bv = *(const bf16x8*)(Vc + vr * 64 + (((ks * 4 + quad) ^ (vr & 7)) * 8));
      oacc[j] = __builtin_amdgcn_mfma_f32_16x16x32_bf16(ap, bv, oacc[j], 0, 0, 0);
    }
  }
  __builtin_amdgcn_s_setprio(0);
}

__global__ __launch_bounds__(256, 3) void flash_kernel(
    const bf16* __restrict__ QKV, const bf16* __restrict__ Vt, bf16* __restrict__ O,
    int* __restrict__ cnt) {
  __shared__ __align__(1024) char smem[40960];
  __shared__ int wsh;
  const int tid = threadIdx.x;
  const int wave = tid >> 6, lane = tid & 63, quad = lane >> 4, l16 = lane & 15;
  const int wbase = tid & ~63;
  const int hloc = wave >> 1, rhalf = wave & 1;
  bf16* Pw = (bf16*)(smem + 32768) + wave * 1024;
  const bf16* Kc = (const bf16*)smem;
  const bf16* Vc = (const bf16*)(smem + 16384);
  // u-invariant swizzle offsets for the named-register prefetch (bf16 elems)
  const int kswz = ((tid & 15) ^ (tid >> 4)) * 8;
  const int vswz = ((tid & 7) ^ ((tid >> 3) & 7)) * 8;
  bf16x8 ones;
#pragma unroll
  for (int e = 0; e < 8; e++) ones[e] = (bf16)1.0f;

  for (;;) {
    if (tid == 0) wsh = atomicAdd(cnt, 1);
    __syncthreads();  // publish wsh; prior item's LDS use fully done
    const int w = wsh;
    if (w >= 1024) break;
    const int qt = 63 - (w >> 4);
    const int b = (w >> 3) & 1, kvh = w & 7;
    const int h = kvh * 2 + hloc;
    const int q0 = qt * 32;
    const int nkt = (qt >> 1) + 1;

    // stage Q [2h x 32 q][128 hd] into K region, chunk-swizzled by row&15
#pragma unroll
    for (int u = 0; u < 4; u++) {
      int g = u * 256 + tid;
      int row = g >> 4, cc = g & 15;
      const bf16* gp = QKV + (size_t)(b * 2048 + q0 + (row & 31)) * 4096 +
                       (kvh * 2 + (row >> 5)) * 128 + ((cc ^ (row & 15)) * 8);
      load16(gp, smem + (u * 256 + wbase) * 16);
    }
    asm volatile("s_waitcnt vmcnt(0)" ::: "memory");
    phase_barrier();  // Q visible to all waves (sched-fenced: aq reads can't hoist)
    bf16x8 aq[4];
    {
      int row = hloc * 32 + rhalf * 16 + l16;
#pragma unroll
      for (int ks = 0; ks < 4; ks++)
        aq[ks] = *(const bf16x8*)((const bf16*)smem + row * 128 +
                                  (((ks * 4 + quad) ^ (row & 15)) * 8));
    }
    __syncthreads();  // aq reads complete (lgkm drained) before K0/V0 overwrite Q

    // stage K/V tile 0 directly to LDS (destination free)
#pragma unroll
    for (int u = 0; u < 4; u++) {
      int g = u * 256 + tid;
      int krow = g >> 4, kcc = g & 15;
      const bf16* kp = QKV + (size_t)(b * 2048 + krow) * 4096 + 2048 +
                       kvh * 128 + ((kcc ^ (krow & 15)) * 8);
      load16(kp, smem + (u * 256 + wbase) * 16);
      int vrow = g >> 3, vcc = g & 7;
      const bf16* vp = Vt + (size_t)(b * 1024 + kvh * 128 + vrow) * 2048 +
                       ((vcc ^ (vrow & 7)) * 8);
      load16(vp, smem + 16384 + (u * 256 + wbase) * 16);
    }
    asm volatile("s_waitcnt vmcnt(0)" ::: "memory");
    phase_barrier();  // tile 0 visible; loop invariant established

    floatx4 oacc[8] = {};
    floatx4 lacc = {};
    const int q0w = q0 + rhalf * 16;

    for (int kt = 0; kt < nkt; kt++) {
      const bool pf = (kt + 1 < nkt);
      floatx4 kr0, kr1, kr2, kr3, vr0, vr1, vr2, vr3;  // named: stays in VGPRs
      if (pf) {
        // T14 issue-early: prefetch tile kt+1 into named registers.
        // K row for u-th load = u*16 + (tid>>4); V row = u*32 + (tid>>3).
        const bf16* kb = QKV + (size_t)(b * 2048 + (kt + 1) * 64 + (tid >> 4)) * 4096 +
                         2048 + kvh * 128 + kswz;
        const bf16* vb = Vt + (size_t)(b * 1024 + kvh * 128 + (tid >> 3)) * 2048 +
                         (kt + 1) * 64 + vswz;
        asm volatile("global_load_dwordx4 %0, %1, off" : "=v"(kr0) : "v"(kb));
        asm volatile("global_load_dwordx4 %0, %1, off" : "=v"(kr1) : "v"(kb + 16 * 4096));
        asm volatile("global_load_dwordx4 %0, %1, off" : "=v"(kr2) : "v"(kb + 32 * 4096));
        asm volatile("global_load_dwordx4 %0, %1, off" : "=v"(kr3) : "v"(kb + 48 * 4096));
        asm volatile("global_load_dwordx4 %0, %1, off" : "=v"(vr0) : "v"(vb));
        asm volatile("global_load_dwordx4 %0, %1, off" : "=v"(vr1) : "v"(vb + 32 * 2048));
        asm volatile("global_load_dwordx4 %0, %1, off" : "=v"(vr2) : "v"(vb + 64 * 2048));
        asm volatile("global_load_dwordx4 %0, %1, off" : "=v"(vr3) : "v"(vb + 96 * 2048));
      }
      if (kt == nkt - 1)
        attn_step32<true>(Kc, Vc, Pw, aq, ones, oacc, lacc, kt * 64, q0w, l16, quad);
      else
        attn_step32<false>(Kc, Vc, Pw, aq, ones, oacc, lacc, kt * 64, q0w, l16, quad);
      phase_barrier();  // A: all waves done reading K/V/P for tile kt
      if (pf) {
        // vmcnt(0): prefetch data in regs. "memory" clobber orders the ds_writes
        // after this wait (stores cannot cross a memory-clobber asm).
        asm volatile("s_waitcnt vmcnt(0)" ::: "memory");
        __builtin_amdgcn_sched_barrier(0);
        char* kd = smem + tid * 16;
        *(floatx4*)(kd)         = kr0;
        *(floatx4*)(kd + 4096)  = kr1;
        *(floatx4*)(kd + 8192)  = kr2;
        *(floatx4*)(kd + 12288) = kr3;
        char* vd = smem + 16384 + tid * 16;
        *(floatx4*)(vd)         = vr0;
        *(floatx4*)(vd + 4096)  = vr1;
        *(floatx4*)(vd + 8192)  = vr2;
        *(floatx4*)(vd + 12288) = vr3;
        asm volatile("s_waitcnt lgkmcnt(0)" ::: "memory");
        __builtin_amdgcn_sched_barrier(0);
        phase_barrier();  // B: tile kt+1 visible to all waves
      }
    }

    // epilogue: O = oacc / rowsum  (lacc has the row sum in every column)
    float rl[4];
#pragma unroll
    for (int r = 0; r < 4; r++) rl[r] = 1.0f / lacc[r];
#pragma unroll
    for (int j = 0; j < 8; j++)
#pragma unroll
      for (int r = 0; r < 4; r++) {
        int s = q0w + quad * 4 + r;
        O[(size_t)(b * 2048 + s) * 2048 + h * 128 + j * 16 + l16] =
            (bf16)(oacc[j][r] * rl[r]);
      }
  }
}

extern "C" void kernel_launch(void* const* d_in, const int* in_sizes, int n_in,
                              void* d_out, int out_size, void* d_ws, size_t ws_size,
                              hipStream_t stream) {
  (void)in_sizes; (void)n_in; (void)out_size; (void)ws_size;
  const float* x    = (const float*)d_in[0];
  const float* cosb = (const float*)d_in[1];
  const float* sinb = (const float*)d_in[2];
  const float* Wq   = (const float*)d_in[3];
  const float* Wk   = (const float*)d_in[4];
  const float* Wv   = (const float*)d_in[5];
  const float* Wo   = (const float*)d_in[6];
  float* out = (float*)d_out;

  char* ws = (char*)d_ws;
  size_t off = 0;
  auto alloc = [&](size_t bytes) { void* p = ws + off; off += bytes; return p; };
  bf16* xb    = (bf16*)alloc(4096ull * 2048 * 2);  // 16 MB
  bf16* WqkvT = (bf16*)alloc(4096ull * 2048 * 2);  // 16 MB  [Wq^T | Wk^T | Wv^T]
  bf16* WoT   = (bf16*)alloc(2048ull * 2048 * 2);  //  8 MB
  bf16* QKV   = (bf16*)alloc(4096ull * 4096 * 2);  // 32 MB  [s][Q 2048 | K 1024 | V 1024]
  bf16* Vtb   = (bf16*)alloc(2048ull * 2048 * 2);  //  8 MB  [b][kv*128+hd][s]
  bf16* Ab    = (bf16*)alloc(4096ull * 2048 * 2);  // 16 MB
  int*  cnt   = (int*)alloc(256);                  // work-steal counter

  // 0. x -> bf16; zero the work counter (stream op, graph-capture safe)
  cvt_kernel<<<8192, 256, 0, stream>>>(x, xb, 2097152);
  hipMemsetAsync(cnt, 0, 256, stream);

  // 1. weight transposes (fp32 -> bf16), one launch
  wtrans_kernel<<<dim3(64, 64, 4), 256, 0, stream>>>(Wq, Wk, Wv, Wo, WqkvT, WoT);

  // 2. fused QKV projection: [4096 s] x [4096 n], 256^2 8-phase
  gemm256<bf16><<<dim3(16, 16), 512, 0, stream>>>(xb, WqkvT, QKV, 4096, 4096, 2048);

  // 3. RoPE on Q and K parts, one launch
  rope_kernel<<<24576, 256, 0, stream>>>(QKV, cosb, sinb);

  // 4. V transpose per batch: [2048 s][1024 c] -> [1024 c][2048 s]
  transpose_bf16<<<dim3(32, 64, 2), 256, 0, stream>>>(
      QKV + 3072, Vtb, 4096, 2048, 2048ll * 4096, 1024ll * 2048);

  // 5. flash attention v5: 3 blocks/CU, named-register T14 prefetch
  flash_kernel<<<dim3(768, 1, 1), 256, 0, stream>>>(QKV, Vtb, Ab, cnt);

  // 6. output projection -> fp32 out, 256^2 8-phase
  gemm256<float><<<dim3(8, 16), 512, 0, stream>>>(Ab, WoT, out, 4096, 2048, 2048);
}

// Round 6
// 352.389 us; speedup vs baseline: 1.0739x; 1.0276x over previous
//
#include <hip/hip_runtime.h>

// B=2, S=2048, D=2048, H=16, KV=8, HD=128, N_REP=2.
// I/O: fp32. Compute: bf16 MFMA, fp32 accum.
//
// Pipeline:
//   0. cvt x fp32 -> bf16 (xb)
//   1. wtrans: Wq/Wk/Wv -> WqkvT [4096 n][2048 k], Wo -> WoT  (one launch)
//   2. gemm256: QKV = xb @ WqkvT          (256x256 8-phase counted-vmcnt)
//   3. rope (Q and K parts, one launch)
//   4. transpose V part per-batch -> Vt[b][kv*128+hd][s]
//   5. flash v7: static items (512 = 32 qt x 2 b x 8 kvh), 4-wave blocks,
//      32 q-rows/wave (2x LDS-read reuse), GQA pair shares K/V, dbuf K/V,
//      counted vmcnt(8), 80 KB LDS = exactly 2 blocks/CU, no work-steal.
//   6. gemm256: out = Ab @ WoT -> d_out (fp32)

typedef __bf16 bf16;
typedef __bf16 bf16x4 __attribute__((ext_vector_type(4)));
typedef __bf16 bf16x8 __attribute__((ext_vector_type(8)));
typedef float floatx4 __attribute__((ext_vector_type(4)));

#define AS1(p) ((const __attribute__((address_space(1))) void*)(p))
#define AS3(p) ((__attribute__((address_space(3))) void*)(p))

__device__ __forceinline__ void load16(const void* g, void* l) {
  __builtin_amdgcn_global_load_lds(AS1(g), AS3(l), 16, 0, 0);
}

__device__ __forceinline__ void phase_barrier() {
  asm volatile("" ::: "memory");
  __builtin_amdgcn_sched_barrier(0);
  __builtin_amdgcn_s_barrier();
  __builtin_amdgcn_sched_barrier(0);
  asm volatile("" ::: "memory");
}

// ---------------- fp32 -> bf16 convert ----------------
__global__ __launch_bounds__(256) void cvt_kernel(const float* __restrict__ in,
                                                  bf16* __restrict__ out, int n4) {
  int i = blockIdx.x * blockDim.x + threadIdx.x;
  if (i >= n4) return;
  float4 v = ((const float4*)in)[i];
  bf16x4 o = {(bf16)v.x, (bf16)v.y, (bf16)v.z, (bf16)v.w};
  ((bf16x4*)out)[i] = o;
}

// ---------------- all 4 weight transposes in one launch ----------------
// out[c*2048 + r] = (bf16)W[r*N + c]; rows always 2048.
__global__ __launch_bounds__(256) void wtrans_kernel(
    const float* __restrict__ Wq, const float* __restrict__ Wk,
    const float* __restrict__ Wv, const float* __restrict__ Wo,
    bf16* __restrict__ WqkvT, bf16* __restrict__ WoT) {
  __shared__ float tile[32][33];
  const int wid = blockIdx.z;
  const float* src = wid == 0 ? Wq : wid == 1 ? Wk : wid == 2 ? Wv : Wo;
  bf16* dst = wid == 0 ? WqkvT
            : wid == 1 ? WqkvT + 2048ull * 2048
            : wid == 2 ? WqkvT + 3072ull * 2048
                       : WoT;
  const int ncols = (wid == 1 || wid == 2) ? 1024 : 2048;
  const int c0 = blockIdx.x * 32, r0 = blockIdx.y * 32;
  if (c0 >= ncols) return;
  const int tx = threadIdx.x & 31, ty = threadIdx.x >> 5;  // 32 x 8
#pragma unroll
  for (int i = 0; i < 4; i++) {
    int ri = ty + i * 8;
    tile[ri][tx] = src[(long)(r0 + ri) * ncols + c0 + tx];
  }
  __syncthreads();
#pragma unroll
  for (int i = 0; i < 4; i++) {
    int ci = ty + i * 8;
    dst[(long)(c0 + ci) * 2048 + r0 + tx] = (bf16)tile[tx][ci];
  }
}

// ---------------- bf16 tiled transpose (for V) ----------------
__global__ __launch_bounds__(256) void transpose_bf16(
    const bf16* __restrict__ in, bf16* __restrict__ out,
    int ldi, int ldo, long ibs, long obs) {
  __shared__ bf16 tile[32][33];
  const long ib = ibs * blockIdx.z, ob = obs * blockIdx.z;
  const int c0 = blockIdx.x * 32, r0 = blockIdx.y * 32;
  const int tx = threadIdx.x & 31, ty = threadIdx.x >> 5;
#pragma unroll
  for (int i = 0; i < 4; i++) {
    int ri = ty + i * 8;
    tile[ri][tx] = in[ib + (long)(r0 + ri) * ldi + c0 + tx];
  }
  __syncthreads();
#pragma unroll
  for (int i = 0; i < 4; i++) {
    int ci = ty + i * 8;
    out[ob + (long)(c0 + ci) * ldo + r0 + tx] = tile[tx][ci];
  }
}

// ---------------- GEMM 256x256, 8-phase: C[M,N] = A[M,K] * Bt[N,K]^T ----------------
// 512 threads = 8 waves (wm = wave>>2 in {0,1}, wn = wave&3 in {0..3}).
// Per-wave output 128x64 = acc[8][4] 16x16 frags.
// LDS per buffer (64KB): A [2 half][8 rg][2 kh][16 r][32 k bf16], B same at +32KB.
// Subtile block = 1024B; swizzle: byte ^= ((byte>>9)&1)<<5 (rows 8-15 flip 32B).
// Requires M%256==0, N%256==0, K%128==0.
template <typename CT>
__global__ __launch_bounds__(512, 2) void gemm256(
    const bf16* __restrict__ A, const bf16* __restrict__ Bt, CT* __restrict__ C,
    int M, int N, int K) {
  __shared__ __align__(1024) char smem[131072];
  const int tid = threadIdx.x;
  const int wave = tid >> 6, lane = tid & 63;
  const int quad = lane >> 4, l16 = lane & 15;
  const int wm = wave >> 2, wn = wave & 3;
  const int m0 = blockIdx.y * 256, n0 = blockIdx.x * 256;

  // staging: per load-instr, wave w writes 1024B block (l*8+w); lane writes 16B
  // at linear byte lane*16; global source is inverse-swizzled.
  const int srow = (wave >> 1) * 16 + (lane >> 2);  // row within 64-row load region
  const int skcol = (wave & 1) * 32 + (((lane & 3) * 8) ^ ((lane & 32) ? 16 : 0));
  const int sblk = wave * 1024;

  // fragment-read offsets (swizzled)
  const int qoff = (quad * 16) ^ ((l16 & 8) << 2);
  const int aoff = wm * 16384 + l16 * 64 + qoff;
  const int boff = 32768 + (wn >> 1) * 16384 + (wn & 1) * 8192 + l16 * 64 + qoff;

  auto stageA = [&](int kt, int h, int buf) {
    const bf16* g = A + (size_t)(m0 + h * 128 + srow) * K + kt * 64 + skcol;
    char* d = smem + buf * 65536 + h * 16384 + sblk;
    load16(g, d);
    load16(g + (size_t)64 * K, d + 8192);
  };
  auto stageB = [&](int kt, int h, int buf) {
    const bf16* g = Bt + (size_t)(n0 + h * 128 + srow) * K + kt * 64 + skcol;
    char* d = smem + buf * 65536 + 32768 + h * 16384 + sblk;
    load16(g, d);
    load16(g + (size_t)64 * K, d + 8192);
  };
  auto rdA = [&](int buf, int fr, int ks) {
    return *(const bf16x8*)(smem + buf * 65536 + aoff + (fr * 2 + ks) * 1024);
  };
  auto rdB = [&](int buf, int fc, int ks) {
    return *(const bf16x8*)(smem + buf * 65536 + boff + (fc * 2 + ks) * 1024);
  };

  floatx4 acc[8][4] = {};

  const int nkt = K >> 6;
  const int niter = nkt >> 1;

  // prologue: tile0 -> buf0 (8 loads), tile1 B halves -> buf1 (4 loads)
  stageB(0, 0, 0); stageB(0, 1, 0);
  stageA(0, 0, 0); stageA(0, 1, 0);
  stageB(1, 0, 1); stageB(1, 1, 1);
  asm volatile("s_waitcnt vmcnt(4)" ::: "memory");
  phase_barrier();

  for (int it = 0; it < niter; ++it) {
    const int T = 2 * it;
    const bool morek = (it < niter - 1);
#pragma unroll
    for (int c = 0; c < 2; ++c) {
      const int buf = c;
      const int tA = T + 1 + c;   // A halves of this tile -> buf^1 (phases 1,2)
      const int tB = T + 2 + c;   // B halves of this tile -> buf   (phases 3,4)
      const bool stA = (c == 0) || morek;

      bf16x8 a[4][2], b01[2][2], b23[2][2];

      // ---- phase 1: Q(0,0) = A rows 0-3 x B cols 0-1 ----
#pragma unroll
      for (int fr = 0; fr < 4; ++fr)
#pragma unroll
        for (int ks = 0; ks < 2; ++ks) a[fr][ks] = rdA(buf, fr, ks);
#pragma unroll
      for (int fc = 0; fc < 2; ++fc)
#pragma unroll
        for (int ks = 0; ks < 2; ++ks) b01[fc][ks] = rdB(buf, fc, ks);
      if (stA) stageA(tA, 0, buf ^ 1);
      phase_barrier();
      __builtin_amdgcn_s_setprio(1);
#pragma unroll
      for (int ks = 0; ks < 2; ++ks)
#pragma unroll
        for (int fr = 0; fr < 4; ++fr)
#pragma unroll
          for (int fc = 0; fc < 2; ++fc)
            acc[fr][fc] = __builtin_amdgcn_mfma_f32_16x16x32_bf16(
                a[fr][ks], b01[fc][ks], acc[fr][fc], 0, 0, 0);
      __builtin_amdgcn_s_setprio(0);
      phase_barrier();

      // ---- phase 2: Q(0,1) = A rows 0-3 x B cols 2-3 ----
#pragma unroll
      for (int fc = 0; fc < 2; ++fc)
#pragma unroll
        for (int ks = 0; ks < 2; ++ks) b23[fc][ks] = rdB(buf, 2 + fc, ks);
      if (stA) stageA(tA, 1, buf ^ 1);
      phase_barrier();
      __builtin_amdgcn_s_setprio(1);
#pragma unroll
      for (int ks = 0; ks < 2; ++ks)
#pragma unroll
        for (int fr = 0; fr < 4; ++fr)
#pragma unroll
          for (int fc = 0; fc < 2; ++fc)
            acc[fr][2 + fc] = __builtin_amdgcn_mfma_f32_16x16x32_bf16(
                a[fr][ks], b23[fc][ks], acc[fr][2 + fc], 0, 0, 0);
      __builtin_amdgcn_s_setprio(0);
      phase_barrier();

      // ---- phase 3: Q(1,1) = A rows 4-7 x B cols 2-3 ----
#pragma unroll
      for (int fr = 0; fr < 4; ++fr)
#pragma unroll
        for (int ks = 0; ks < 2; ++ks) a[fr][ks] = rdA(buf, 4 + fr, ks);
      if (morek) stageB(tB, 0, buf);
      phase_barrier();
      __builtin_amdgcn_s_setprio(1);
#pragma unroll
      for (int ks = 0; ks < 2; ++ks)
#pragma unroll
        for (int fr = 0; fr < 4; ++fr)
#pragma unroll
          for (int fc = 0; fc < 2; ++fc)
            acc[4 + fr][2 + fc] = __builtin_amdgcn_mfma_f32_16x16x32_bf16(
                a[fr][ks], b23[fc][ks], acc[4 + fr][2 + fc], 0, 0, 0);
      __builtin_amdgcn_s_setprio(0);
      phase_barrier();

      // ---- phase 4: Q(1,0) = A rows 4-7 x B cols 0-1 ----
      if (morek) stageB(tB, 1, buf);
      if (morek)
        asm volatile("s_waitcnt vmcnt(4)" ::: "memory");
      else
        asm volatile("s_waitcnt vmcnt(0)" ::: "memory");
      phase_barrier();
      __builtin_amdgcn_s_setprio(1);
#pragma unroll
      for (int ks = 0; ks < 2; ++ks)
#pragma unroll
        for (int fr = 0; fr < 4; ++fr)
#pragma unroll
          for (int fc = 0; fc < 2; ++fc)
            acc[4 + fr][fc] = __builtin_amdgcn_mfma_f32_16x16x32_bf16(
                a[fr][ks], b01[fc][ks], acc[4 + fr][fc], 0, 0, 0);
      __builtin_amdgcn_s_setprio(0);
      phase_barrier();
    }
  }

  // epilogue
#pragma unroll
  for (int fr = 0; fr < 8; ++fr)
#pragma unroll
    for (int fc = 0; fc < 4; ++fc)
#pragma unroll
      for (int r = 0; r < 4; ++r) {
        int row = m0 + wm * 128 + fr * 16 + quad * 4 + r;
        int col = n0 + wn * 64 + fc * 16 + l16;
        C[(size_t)row * N + col] = (CT)acc[fr][fc][r];
      }
}

// ---------------- RoPE, Q part + K part in one launch ----------------
__global__ void rope_kernel(bf16* __restrict__ QKV, const float* __restrict__ cosb,
                            const float* __restrict__ sinb) {
  int idx = blockIdx.x * blockDim.x + threadIdx.x;
  if (idx >= 6291456) return;
  int nh, nhs, offc;
  if (idx < 4194304) { nh = 16; nhs = 4; offc = 0; }
  else { idx -= 4194304; nh = 8; nhs = 3; offc = 2048; }
  int d = idx & 63;
  int rest = idx >> 6;
  int hh = rest & (nh - 1);
  int bs = rest >> nhs;  // b*2048 + s
  int s = bs & 2047;
  size_t base = (size_t)bs * 4096 + offc + hh * 128;
  float c0 = cosb[s * 128 + d];
  float c1 = cosb[s * 128 + d + 64];
  float s0 = sinb[s * 128 + d];
  float s1 = sinb[s * 128 + d + 64];
  float x0 = (float)QKV[base + d];
  float x1 = (float)QKV[base + d + 64];
  QKV[base + d] = (bf16)(x0 * c0 - x1 * s0);
  QKV[base + d + 64] = (bf16)(x1 * c1 + x0 * s1);
}

// ---------------- Flash v7: static items, 32 q-rows/wave, dbuf K/V ----------------
// Items: w = blockIdx.x in [0,512): g = w>>4; qt = g<16 ? 31-g : g-16
// (pairs long+short items on the same CU across the 2 dispatch rounds),
// b = (w>>3)&1, kvh = w&7. Block = 256 threads (4 waves).
// Wave (hloc = wave>>1, rhalf = wave&1): head h = 2*kvh + hloc,
// q-rows [qt*64 + rhalf*32, +32). K-tile = 64 keys, nkt = qt + 1.
// LDS (80 KB -> exactly 2 blocks/CU; NO other shared vars!):
//      K0/K1 [64 key][128 hd] swz&15   16 KB @ 0, 16K   (K0+K1 = Q staging, 128 rows)
//      V0/V1 [128 hd][64 key] swz&7    16 KB @ 32K, 48K
//      P [wave][32 q][64 k] swz&7       4 KB/wave @ 64K
// Per tile-wave: 36 ds_read_b128 serving 68 MFMA (2x reuse via 2 q-rowfrags).
// v3-style staging: dbuf, counted vmcnt(8), 2 fenced barriers/tile.

template <bool MASK>
__device__ __forceinline__ void attn_tile64(
    const bf16* Ksw, const bf16* Vsw, bf16* Pw, const bf16x8 (&aq)[2][4],
    const bf16x8& ones, floatx4 (&oacc)[2][8], floatx4 (&lacc)[2],
    int k0, int q0w, int l16, int quad) {
  floatx4 sacc[2][4] = {};
  __builtin_amdgcn_s_setprio(1);
#pragma unroll
  for (int ks = 0; ks < 4; ks++) {
#pragma unroll
    for (int j = 0; j < 4; j++) {
      int row = j * 16 + l16;
      bf16x8 bk = *(const bf16x8*)(Ksw + row * 128 + (((ks * 4 + quad) ^ (row & 15)) * 8));
      sacc[0][j] = __builtin_amdgcn_mfma_f32_16x16x32_bf16(aq[0][ks], bk, sacc[0][j], 0, 0, 0);
      sacc[1][j] = __builtin_amdgcn_mfma_f32_16x16x32_bf16(aq[1][ks], bk, sacc[1][j], 0, 0, 0);
    }
  }
  __builtin_amdgcn_s_setprio(0);
  const float C = 0.12752188659023044f;  // (1/sqrt(128)) * log2(e)
#pragma unroll
  for (int i = 0; i < 2; i++)
#pragma unroll
    for (int r = 0; r < 4; r++) {
      int row = i * 16 + quad * 4 + r;
#pragma unroll
      for (int j = 0; j < 4; j++) {
        float p = exp2f(sacc[i][j][r] * C);
        if (MASK) {
          int key = k0 + j * 16 + l16;
          int qi = q0w + row;
          if (key > qi) p = 0.f;
        }
        int col = j * 16 + l16;
        Pw[row * 64 + (((col >> 3) ^ (row & 7)) * 8) + (col & 7)] = (bf16)p;
      }
    }
  __builtin_amdgcn_s_setprio(1);
#pragma unroll
  for (int ks = 0; ks < 2; ks++) {
    bf16x8 ap0 = *(const bf16x8*)(Pw + l16 * 64 + (((ks * 4 + quad) ^ (l16 & 7)) * 8));
    bf16x8 ap1 = *(const bf16x8*)(Pw + (16 + l16) * 64 + (((ks * 4 + quad) ^ (l16 & 7)) * 8));
    lacc[0] = __builtin_amdgcn_mfma_f32_16x16x32_bf16(ap0, ones, lacc[0], 0, 0, 0);
    lacc[1] = __builtin_amdgcn_mfma_f32_16x16x32_bf16(ap1, ones, lacc[1], 0, 0, 0);
#pragma unroll
    for (int j = 0; j < 8; j++) {
      int vr = j * 16 + l16;
      bf16x8 bv = *(const bf16x8*)(Vsw + vr * 64 + (((ks * 4 + quad) ^ (vr & 7)) * 8));
      oacc[0][j] = __builtin_amdgcn_mfma_f32_16x16x32_bf16(ap0, bv, oacc[0][j], 0, 0, 0);
      oacc[1][j] = __builtin_amdgcn_mfma_f32_16x16x32_bf16(ap1, bv, oacc[1][j], 0, 0, 0);
    }
  }
  __builtin_amdgcn_s_setprio(0);
}

__global__ __launch_bounds__(256, 2) void flash_kernel(
    const bf16* __restrict__ QKV, const bf16* __restrict__ Vt, bf16* __restrict__ O) {
  __shared__ __align__(1024) char smem[81920];
  const int tid = threadIdx.x;
  const int wave = tid >> 6, lane = tid & 63, quad = lane >> 4, l16 = lane & 15;
  const int wbase = tid & ~63;
  const int hloc = wave >> 1, rhalf = wave & 1;
  bf16* Pw = (bf16*)(smem + 65536) + wave * 2048;
  bf16x8 ones;
#pragma unroll
  for (int e = 0; e < 8; e++) ones[e] = (bf16)1.0f;

  const int w = blockIdx.x;
  const int g = w >> 4;
  const int qt = (g < 16) ? (31 - g) : (g - 16);  // balance: round1 long, round2 short
  const int b = (w >> 3) & 1, kvh = w & 7;
  const int h = kvh * 2 + hloc;
  const int q0 = qt * 64;
  const int nkt = qt + 1;

  // stage Q [2 heads x 64 q][128 hd] into K0+K1 region (32 KB), swz row&15
#pragma unroll
  for (int u = 0; u < 8; u++) {
    int gg = u * 256 + tid;
    int row = gg >> 4, cc = gg & 15;  // row 0..127: head = row>>6, qrow = row&63
    const bf16* gp = QKV + (size_t)(b * 2048 + q0 + (row & 63)) * 4096 +
                     (kvh * 2 + (row >> 6)) * 128 + ((cc ^ (row & 15)) * 8);
    load16(gp, smem + (u * 256 + wbase) * 16);
  }
  asm volatile("s_waitcnt vmcnt(0)" ::: "memory");
  phase_barrier();  // Q visible (sched-fenced: aq reads can't hoist above)
  bf16x8 aq[2][4];
#pragma unroll
  for (int i = 0; i < 2; i++)
#pragma unroll
    for (int ks = 0; ks < 4; ks++) {
      int qr = hloc * 64 + rhalf * 32 + i * 16 + l16;
      aq[i][ks] = *(const bf16x8*)((const bf16*)smem + qr * 128 +
                                   (((ks * 4 + quad) ^ (qr & 15)) * 8));
    }
  __syncthreads();  // all aq extracted before K0 region is overwritten

  // stage K/V tile kt -> buffer nb (8 loads/thread)
  auto stageKV = [&](int kt, int nb) {
    char* kd = smem + nb * 16384;
    char* vd = smem + 32768 + nb * 16384;
#pragma unroll
    for (int u = 0; u < 4; u++) {
      int gg = u * 256 + tid;
      int krow = gg >> 4, kcc = gg & 15;
      const bf16* kp = QKV + (size_t)(b * 2048 + kt * 64 + krow) * 4096 + 2048 +
                       kvh * 128 + ((kcc ^ (krow & 15)) * 8);
      load16(kp, kd + (u * 256 + wbase) * 16);
      int vrow = gg >> 3, vcc = gg & 7;
      const bf16* vp = Vt + (size_t)(b * 1024 + kvh * 128 + vrow) * 2048 + kt * 64 +
                       ((vcc ^ (vrow & 7)) * 8);
      load16(vp, vd + (u * 256 + wbase) * 16);
    }
  };

  stageKV(0, 0);

  floatx4 oacc[2][8] = {};
  floatx4 lacc[2] = {};
  const int q0w = q0 + rhalf * 32;

  for (int kt = 0; kt < nkt; kt++) {
    const int cur = kt & 1;
    if (kt + 1 < nkt) {
      stageKV(kt + 1, cur ^ 1);  // prefetch next tile (dest last read at kt-1,
                                 // protected by kt-1's trailing barrier)
      asm volatile("s_waitcnt vmcnt(8)" ::: "memory");  // own tile-kt loads done
    } else {
      asm volatile("s_waitcnt vmcnt(0)" ::: "memory");
    }
    phase_barrier();  // tile kt globally visible
    const bf16* Kc = (const bf16*)(smem + cur * 16384);
    const bf16* Vc = (const bf16*)(smem + 32768 + cur * 16384);
    if (kt == nkt - 1)
      attn_tile64<true>(Kc, Vc, Pw, aq, ones, oacc, lacc, kt * 64, q0w, l16, quad);
    else
      attn_tile64<false>(Kc, Vc, Pw, aq, ones, oacc, lacc, kt * 64, q0w, l16, quad);
    phase_barrier();  // all waves done reading K/V[cur] before it is restaged
  }

  // epilogue: O = oacc / rowsum  (lacc has the row sum in every column)
  float rl[2][4];
#pragma unroll
  for (int i = 0; i < 2; i++)
#pragma unroll
    for (int r = 0; r < 4; r++) rl[i][r] = 1.0f / lacc[i][r];
#pragma unroll
  for (int i = 0; i < 2; i++)
#pragma unroll
    for (int j = 0; j < 8; j++)
#pragma unroll
      for (int r = 0; r < 4; r++) {
        int s = q0w + i * 16 + quad * 4 + r;
        O[(size_t)(b * 2048 + s) * 2048 + h * 128 + j * 16 + l16] =
            (bf16)(oacc[i][j][r] * rl[i][r]);
      }
}

extern "C" void kernel_launch(void* const* d_in, const int* in_sizes, int n_in,
                              void* d_out, int out_size, void* d_ws, size_t ws_size,
                              hipStream_t stream) {
  (void)in_sizes; (void)n_in; (void)out_size; (void)ws_size;
  const float* x    = (const float*)d_in[0];
  const float* cosb = (const float*)d_in[1];
  const float* sinb = (const float*)d_in[2];
  const float* Wq   = (const float*)d_in[3];
  const float* Wk   = (const float*)d_in[4];
  const float* Wv   = (const float*)d_in[5];
  const float* Wo   = (const float*)d_in[6];
  float* out = (float*)d_out;

  char* ws = (char*)d_ws;
  size_t off = 0;
  auto alloc = [&](size_t bytes) { void* p = ws + off; off += bytes; return p; };
  bf16* xb    = (bf16*)alloc(4096ull * 2048 * 2);  // 16 MB
  bf16* WqkvT = (bf16*)alloc(4096ull * 2048 * 2);  // 16 MB  [Wq^T | Wk^T | Wv^T]
  bf16* WoT   = (bf16*)alloc(2048ull * 2048 * 2);  //  8 MB
  bf16* QKV   = (bf16*)alloc(4096ull * 4096 * 2);  // 32 MB  [s][Q 2048 | K 1024 | V 1024]
  bf16* Vtb   = (bf16*)alloc(2048ull * 2048 * 2);  //  8 MB  [b][kv*128+hd][s]
  bf16* Ab    = (bf16*)alloc(4096ull * 2048 * 2);  // 16 MB

  // 0. x -> bf16
  cvt_kernel<<<8192, 256, 0, stream>>>(x, xb, 2097152);

  // 1. weight transposes (fp32 -> bf16), one launch
  wtrans_kernel<<<dim3(64, 64, 4), 256, 0, stream>>>(Wq, Wk, Wv, Wo, WqkvT, WoT);

  // 2. fused QKV projection: [4096 s] x [4096 n], 256^2 8-phase
  gemm256<bf16><<<dim3(16, 16), 512, 0, stream>>>(xb, WqkvT, QKV, 4096, 4096, 2048);

  // 3. RoPE on Q and K parts, one launch
  rope_kernel<<<24576, 256, 0, stream>>>(QKV, cosb, sinb);

  // 4. V transpose per batch: [2048 s][1024 c] -> [1024 c][2048 s]
  transpose_bf16<<<dim3(32, 64, 2), 256, 0, stream>>>(
      QKV + 3072, Vtb, 4096, 2048, 2048ll * 4096, 1024ll * 2048);

  // 5. flash attention v7: 512 static items, 32 q-rows/wave, 2 blocks/CU
  flash_kernel<<<dim3(512, 1, 1), 256, 0, stream>>>(QKV, Vtb, Ab);

  // 6. output projection -> fp32 out, 256^2 8-phase
  gemm256<float><<<dim3(8, 16), 512, 0, stream>>>(Ab, WoT, out, 4096, 2048, 2048);
}

// Round 7
// 342.143 us; speedup vs baseline: 1.1060x; 1.0299x over previous
//
#include <hip/hip_runtime.h>

// B=2, S=2048, D=2048, H=16, KV=8, HD=128, N_REP=2.
// I/O: fp32. Compute: bf16 MFMA, fp32 accum.
//
// Pipeline:
//   0. cvt x fp32 -> bf16 (xb)
//   1. wtrans: Wq/Wk/Wv -> WqkvT [4096 n][2048 k], Wo -> WoT  (one launch)
//   2. gemm256: QKV = xb @ WqkvT          (256x256 8-phase counted-vmcnt)
//   3. rope (Q and K parts, one launch)
//   4. transpose V part per-batch -> Vt[b][kv*128+hd][s]
//   5. flash v8: 8-wave blocks (512 thr), 2 heads x 4 rowgroups x 16 q-rows,
//      v3's lean 104-VGPR wave shape, dbuf K/V + counted vmcnt(4),
//      80 KB LDS -> 2 blocks/CU = 16 waves/CU, bit-0 qt pairing (2c/2c+1
//      complementary) for consecutive-co-CU balance. Static items, no steal.
//   6. gemm256: out = Ab @ WoT -> d_out (fp32)

typedef __bf16 bf16;
typedef __bf16 bf16x4 __attribute__((ext_vector_type(4)));
typedef __bf16 bf16x8 __attribute__((ext_vector_type(8)));
typedef float floatx4 __attribute__((ext_vector_type(4)));

#define AS1(p) ((const __attribute__((address_space(1))) void*)(p))
#define AS3(p) ((__attribute__((address_space(3))) void*)(p))

__device__ __forceinline__ void load16(const void* g, void* l) {
  __builtin_amdgcn_global_load_lds(AS1(g), AS3(l), 16, 0, 0);
}

__device__ __forceinline__ void phase_barrier() {
  asm volatile("" ::: "memory");
  __builtin_amdgcn_sched_barrier(0);
  __builtin_amdgcn_s_barrier();
  __builtin_amdgcn_sched_barrier(0);
  asm volatile("" ::: "memory");
}

// ---------------- fp32 -> bf16 convert ----------------
__global__ __launch_bounds__(256) void cvt_kernel(const float* __restrict__ in,
                                                  bf16* __restrict__ out, int n4) {
  int i = blockIdx.x * blockDim.x + threadIdx.x;
  if (i >= n4) return;
  float4 v = ((const float4*)in)[i];
  bf16x4 o = {(bf16)v.x, (bf16)v.y, (bf16)v.z, (bf16)v.w};
  ((bf16x4*)out)[i] = o;
}

// ---------------- all 4 weight transposes in one launch ----------------
// out[c*2048 + r] = (bf16)W[r*N + c]; rows always 2048.
__global__ __launch_bounds__(256) void wtrans_kernel(
    const float* __restrict__ Wq, const float* __restrict__ Wk,
    const float* __restrict__ Wv, const float* __restrict__ Wo,
    bf16* __restrict__ WqkvT, bf16* __restrict__ WoT) {
  __shared__ float tile[32][33];
  const int wid = blockIdx.z;
  const float* src = wid == 0 ? Wq : wid == 1 ? Wk : wid == 2 ? Wv : Wo;
  bf16* dst = wid == 0 ? WqkvT
            : wid == 1 ? WqkvT + 2048ull * 2048
            : wid == 2 ? WqkvT + 3072ull * 2048
                       : WoT;
  const int ncols = (wid == 1 || wid == 2) ? 1024 : 2048;
  const int c0 = blockIdx.x * 32, r0 = blockIdx.y * 32;
  if (c0 >= ncols) return;
  const int tx = threadIdx.x & 31, ty = threadIdx.x >> 5;  // 32 x 8
#pragma unroll
  for (int i = 0; i < 4; i++) {
    int ri = ty + i * 8;
    tile[ri][tx] = src[(long)(r0 + ri) * ncols + c0 + tx];
  }
  __syncthreads();
#pragma unroll
  for (int i = 0; i < 4; i++) {
    int ci = ty + i * 8;
    dst[(long)(c0 + ci) * 2048 + r0 + tx] = (bf16)tile[tx][ci];
  }
}

// ---------------- bf16 tiled transpose (for V) ----------------
__global__ __launch_bounds__(256) void transpose_bf16(
    const bf16* __restrict__ in, bf16* __restrict__ out,
    int ldi, int ldo, long ibs, long obs) {
  __shared__ bf16 tile[32][33];
  const long ib = ibs * blockIdx.z, ob = obs * blockIdx.z;
  const int c0 = blockIdx.x * 32, r0 = blockIdx.y * 32;
  const int tx = threadIdx.x & 31, ty = threadIdx.x >> 5;
#pragma unroll
  for (int i = 0; i < 4; i++) {
    int ri = ty + i * 8;
    tile[ri][tx] = in[ib + (long)(r0 + ri) * ldi + c0 + tx];
  }
  __syncthreads();
#pragma unroll
  for (int i = 0; i < 4; i++) {
    int ci = ty + i * 8;
    out[ob + (long)(c0 + ci) * ldo + r0 + tx] = tile[tx][ci];
  }
}

// ---------------- GEMM 256x256, 8-phase: C[M,N] = A[M,K] * Bt[N,K]^T ----------------
// 512 threads = 8 waves (wm = wave>>2 in {0,1}, wn = wave&3 in {0..3}).
// Per-wave output 128x64 = acc[8][4] 16x16 frags.
// LDS per buffer (64KB): A [2 half][8 rg][2 kh][16 r][32 k bf16], B same at +32KB.
// Subtile block = 1024B; swizzle: byte ^= ((byte>>9)&1)<<5 (rows 8-15 flip 32B).
// Requires M%256==0, N%256==0, K%128==0.
template <typename CT>
__global__ __launch_bounds__(512, 2) void gemm256(
    const bf16* __restrict__ A, const bf16* __restrict__ Bt, CT* __restrict__ C,
    int M, int N, int K) {
  __shared__ __align__(1024) char smem[131072];
  const int tid = threadIdx.x;
  const int wave = tid >> 6, lane = tid & 63;
  const int quad = lane >> 4, l16 = lane & 15;
  const int wm = wave >> 2, wn = wave & 3;
  const int m0 = blockIdx.y * 256, n0 = blockIdx.x * 256;

  // staging: per load-instr, wave w writes 1024B block (l*8+w); lane writes 16B
  // at linear byte lane*16; global source is inverse-swizzled.
  const int srow = (wave >> 1) * 16 + (lane >> 2);  // row within 64-row load region
  const int skcol = (wave & 1) * 32 + (((lane & 3) * 8) ^ ((lane & 32) ? 16 : 0));
  const int sblk = wave * 1024;

  // fragment-read offsets (swizzled)
  const int qoff = (quad * 16) ^ ((l16 & 8) << 2);
  const int aoff = wm * 16384 + l16 * 64 + qoff;
  const int boff = 32768 + (wn >> 1) * 16384 + (wn & 1) * 8192 + l16 * 64 + qoff;

  auto stageA = [&](int kt, int h, int buf) {
    const bf16* g = A + (size_t)(m0 + h * 128 + srow) * K + kt * 64 + skcol;
    char* d = smem + buf * 65536 + h * 16384 + sblk;
    load16(g, d);
    load16(g + (size_t)64 * K, d + 8192);
  };
  auto stageB = [&](int kt, int h, int buf) {
    const bf16* g = Bt + (size_t)(n0 + h * 128 + srow) * K + kt * 64 + skcol;
    char* d = smem + buf * 65536 + 32768 + h * 16384 + sblk;
    load16(g, d);
    load16(g + (size_t)64 * K, d + 8192);
  };
  auto rdA = [&](int buf, int fr, int ks) {
    return *(const bf16x8*)(smem + buf * 65536 + aoff + (fr * 2 + ks) * 1024);
  };
  auto rdB = [&](int buf, int fc, int ks) {
    return *(const bf16x8*)(smem + buf * 65536 + boff + (fc * 2 + ks) * 1024);
  };

  floatx4 acc[8][4] = {};

  const int nkt = K >> 6;
  const int niter = nkt >> 1;

  // prologue: tile0 -> buf0 (8 loads), tile1 B halves -> buf1 (4 loads)
  stageB(0, 0, 0); stageB(0, 1, 0);
  stageA(0, 0, 0); stageA(0, 1, 0);
  stageB(1, 0, 1); stageB(1, 1, 1);
  asm volatile("s_waitcnt vmcnt(4)" ::: "memory");
  phase_barrier();

  for (int it = 0; it < niter; ++it) {
    const int T = 2 * it;
    const bool morek = (it < niter - 1);
#pragma unroll
    for (int c = 0; c < 2; ++c) {
      const int buf = c;
      const int tA = T + 1 + c;   // A halves of this tile -> buf^1 (phases 1,2)
      const int tB = T + 2 + c;   // B halves of this tile -> buf   (phases 3,4)
      const bool stA = (c == 0) || morek;

      bf16x8 a[4][2], b01[2][2], b23[2][2];

      // ---- phase 1: Q(0,0) = A rows 0-3 x B cols 0-1 ----
#pragma unroll
      for (int fr = 0; fr < 4; ++fr)
#pragma unroll
        for (int ks = 0; ks < 2; ++ks) a[fr][ks] = rdA(buf, fr, ks);
#pragma unroll
      for (int fc = 0; fc < 2; ++fc)
#pragma unroll
        for (int ks = 0; ks < 2; ++ks) b01[fc][ks] = rdB(buf, fc, ks);
      if (stA) stageA(tA, 0, buf ^ 1);
      phase_barrier();
      __builtin_amdgcn_s_setprio(1);
#pragma unroll
      for (int ks = 0; ks < 2; ++ks)
#pragma unroll
        for (int fr = 0; fr < 4; ++fr)
#pragma unroll
          for (int fc = 0; fc < 2; ++fc)
            acc[fr][fc] = __builtin_amdgcn_mfma_f32_16x16x32_bf16(
                a[fr][ks], b01[fc][ks], acc[fr][fc], 0, 0, 0);
      __builtin_amdgcn_s_setprio(0);
      phase_barrier();

      // ---- phase 2: Q(0,1) = A rows 0-3 x B cols 2-3 ----
#pragma unroll
      for (int fc = 0; fc < 2; ++fc)
#pragma unroll
        for (int ks = 0; ks < 2; ++ks) b23[fc][ks] = rdB(buf, 2 + fc, ks);
      if (stA) stageA(tA, 1, buf ^ 1);
      phase_barrier();
      __builtin_amdgcn_s_setprio(1);
#pragma unroll
      for (int ks = 0; ks < 2; ++ks)
#pragma unroll
        for (int fr = 0; fr < 4; ++fr)
#pragma unroll
          for (int fc = 0; fc < 2; ++fc)
            acc[fr][2 + fc] = __builtin_amdgcn_mfma_f32_16x16x32_bf16(
                a[fr][ks], b23[fc][ks], acc[fr][2 + fc], 0, 0, 0);
      __builtin_amdgcn_s_setprio(0);
      phase_barrier();

      // ---- phase 3: Q(1,1) = A rows 4-7 x B cols 2-3 ----
#pragma unroll
      for (int fr = 0; fr < 4; ++fr)
#pragma unroll
        for (int ks = 0; ks < 2; ++ks) a[fr][ks] = rdA(buf, 4 + fr, ks);
      if (morek) stageB(tB, 0, buf);
      phase_barrier();
      __builtin_amdgcn_s_setprio(1);
#pragma unroll
      for (int ks = 0; ks < 2; ++ks)
#pragma unroll
        for (int fr = 0; fr < 4; ++fr)
#pragma unroll
          for (int fc = 0; fc < 2; ++fc)
            acc[4 + fr][2 + fc] = __builtin_amdgcn_mfma_f32_16x16x32_bf16(
                a[fr][ks], b23[fc][ks], acc[4 + fr][2 + fc], 0, 0, 0);
      __builtin_amdgcn_s_setprio(0);
      phase_barrier();

      // ---- phase 4: Q(1,0) = A rows 4-7 x B cols 0-1 ----
      if (morek) stageB(tB, 1, buf);
      if (morek)
        asm volatile("s_waitcnt vmcnt(4)" ::: "memory");
      else
        asm volatile("s_waitcnt vmcnt(0)" ::: "memory");
      phase_barrier();
      __builtin_amdgcn_s_setprio(1);
#pragma unroll
      for (int ks = 0; ks < 2; ++ks)
#pragma unroll
        for (int fr = 0; fr < 4; ++fr)
#pragma unroll
          for (int fc = 0; fc < 2; ++fc)
            acc[4 + fr][fc] = __builtin_amdgcn_mfma_f32_16x16x32_bf16(
                a[fr][ks], b01[fc][ks], acc[4 + fr][fc], 0, 0, 0);
      __builtin_amdgcn_s_setprio(0);
      phase_barrier();
    }
  }

  // epilogue
#pragma unroll
  for (int fr = 0; fr < 8; ++fr)
#pragma unroll
    for (int fc = 0; fc < 4; ++fc)
#pragma unroll
      for (int r = 0; r < 4; ++r) {
        int row = m0 + wm * 128 + fr * 16 + quad * 4 + r;
        int col = n0 + wn * 64 + fc * 16 + l16;
        C[(size_t)row * N + col] = (CT)acc[fr][fc][r];
      }
}

// ---------------- RoPE, Q part + K part in one launch ----------------
__global__ void rope_kernel(bf16* __restrict__ QKV, const float* __restrict__ cosb,
                            const float* __restrict__ sinb) {
  int idx = blockIdx.x * blockDim.x + threadIdx.x;
  if (idx >= 6291456) return;
  int nh, nhs, offc;
  if (idx < 4194304) { nh = 16; nhs = 4; offc = 0; }
  else { idx -= 4194304; nh = 8; nhs = 3; offc = 2048; }
  int d = idx & 63;
  int rest = idx >> 6;
  int hh = rest & (nh - 1);
  int bs = rest >> nhs;  // b*2048 + s
  int s = bs & 2047;
  size_t base = (size_t)bs * 4096 + offc + hh * 128;
  float c0 = cosb[s * 128 + d];
  float c1 = cosb[s * 128 + d + 64];
  float s0 = sinb[s * 128 + d];
  float s1 = sinb[s * 128 + d + 64];
  float x0 = (float)QKV[base + d];
  float x1 = (float)QKV[base + d + 64];
  QKV[base + d] = (bf16)(x0 * c0 - x1 * s0);
  QKV[base + d + 64] = (bf16)(x1 * c1 + x0 * s1);
}

// ---------------- Flash v8: 8-wave blocks, static bit-0-paired items ----------------
// Items: w = blockIdx.x in [0,512): side = w&1, kvh = (w>>1)&7, b = (w>>4)&1,
// g = w>>5 (0..15); qt = side ? 31-g : g.  Blocks 2c,2c+1 share (b,kvh) and get
// complementary qt (g, 31-g) -> consecutive-co-CU pairs do exactly 33 tiles.
// Block = 512 threads (8 waves). Wave: hloc = wave&1, rgroup = wave>>1 (0..3);
// head h = 2*kvh + hloc, q-rows [qt*64 + rgroup*16, +16). K-tile = 64, nkt = qt+1.
// LDS (80 KB exactly -> 2 blocks/CU = 16 waves/CU):
//      K0/K1 [64 key][128 hd] swz&15   16 KB @ 0, 16K   (K0+K1 = Q staging, 128 rows)
//      V0/V1 [128 hd][64 key] swz&7    16 KB @ 32K, 48K
//      P [wave][16 q][64 k] swz&7       2 KB/wave x 8 @ 64K
// Staging: 4 load16/thread/tile; dbuf; counted vmcnt(4); 2 fenced barriers/tile.
// Per-wave state = v3's lean shape (aq[4], oacc[8]) -> ~104 VGPR, no spill.

template <bool MASK>
__device__ __forceinline__ void attn_step32(
    const bf16* Kc, const bf16* Vc, bf16* Pw, const bf16x8 (&aq)[4],
    const bf16x8& ones, floatx4 (&oacc)[8], floatx4& lacc,
    int k0, int q0w, int l16, int quad) {
  floatx4 sacc[4] = {};
  __builtin_amdgcn_s_setprio(1);
#pragma unroll
  for (int ks = 0; ks < 4; ks++)
#pragma unroll
    for (int j = 0; j < 4; j++) {
      int row = j * 16 + l16;
      bf16x8 bk = *(const bf16x8*)(Kc + row * 128 + (((ks * 4 + quad) ^ (row & 15)) * 8));
      sacc[j] = __builtin_amdgcn_mfma_f32_16x16x32_bf16(aq[ks], bk, sacc[j], 0, 0, 0);
    }
  __builtin_amdgcn_s_setprio(0);
  const float C = 0.12752188659023044f;  // (1/sqrt(128)) * log2(e)
#pragma unroll
  for (int r = 0; r < 4; r++) {
    int row = quad * 4 + r;
#pragma unroll
    for (int j = 0; j < 4; j++) {
      float p = exp2f(sacc[j][r] * C);
      if (MASK) {
        int key = k0 + j * 16 + l16;
        if (key > q0w + row) p = 0.f;
      }
      int col = j * 16 + l16;
      Pw[row * 64 + (((col >> 3) ^ (row & 7)) * 8) + (col & 7)] = (bf16)p;
    }
  }
  __builtin_amdgcn_s_setprio(1);
#pragma unroll
  for (int ks = 0; ks < 2; ks++) {
    bf16x8 ap = *(const bf16x8*)(Pw + l16 * 64 + (((ks * 4 + quad) ^ (l16 & 7)) * 8));
    lacc = __builtin_amdgcn_mfma_f32_16x16x32_bf16(ap, ones, lacc, 0, 0, 0);
#pragma unroll
    for (int j = 0; j < 8; j++) {
      int vr = j * 16 + l16;
      bf16x8 bv = *(const bf16x8*)(Vc + vr * 64 + (((ks * 4 + quad) ^ (vr & 7)) * 8));
      oacc[j] = __builtin_amdgcn_mfma_f32_16x16x32_bf16(ap, bv, oacc[j], 0, 0, 0);
    }
  }
  __builtin_amdgcn_s_setprio(0);
}

__global__ __launch_bounds__(512, 4) void flash_kernel(
    const bf16* __restrict__ QKV, const bf16* __restrict__ Vt, bf16* __restrict__ O) {
  __shared__ __align__(1024) char smem[81920];
  const int tid = threadIdx.x;
  const int wave = tid >> 6, lane = tid & 63, quad = lane >> 4, l16 = lane & 15;
  const int wbase = tid & ~63;
  const int hloc = wave & 1, rgroup = wave >> 1;
  bf16* Pw = (bf16*)(smem + 65536) + wave * 1024;  // 16x64 bf16 = 2 KB/wave
  bf16x8 ones;
#pragma unroll
  for (int e = 0; e < 8; e++) ones[e] = (bf16)1.0f;

  const int w = blockIdx.x;
  const int side = w & 1, kvh = (w >> 1) & 7, b = (w >> 4) & 1, g = w >> 5;
  const int qt = side ? 31 - g : g;
  const int h = kvh * 2 + hloc;
  const int q0 = qt * 64;
  const int nkt = qt + 1;

  // stage Q [2 heads x 64 q][128 hd] into K0+K1 region (32 KB), swz row&15
#pragma unroll
  for (int u = 0; u < 4; u++) {
    int gg = u * 512 + tid;
    int row = gg >> 4, cc = gg & 15;  // row 0..127: head = row>>6, qrow = row&63
    const bf16* gp = QKV + (size_t)(b * 2048 + q0 + (row & 63)) * 4096 +
                     (kvh * 2 + (row >> 6)) * 128 + ((cc ^ (row & 15)) * 8);
    load16(gp, smem + (u * 512 + wbase) * 16);
  }
  asm volatile("s_waitcnt vmcnt(0)" ::: "memory");
  phase_barrier();  // Q visible (sched-fenced: aq reads can't hoist above)
  bf16x8 aq[4];
  {
    int qr = hloc * 64 + rgroup * 16 + l16;  // LDS row 0..127
#pragma unroll
    for (int ks = 0; ks < 4; ks++)
      aq[ks] = *(const bf16x8*)((const bf16*)smem + qr * 128 +
                                (((ks * 4 + quad) ^ (qr & 15)) * 8));
  }
  __syncthreads();  // all aq extracted before K0/K1 region is overwritten

  // stage K/V tile kt -> buffer nb (4 loads/thread)
  auto stageKV = [&](int kt, int nb) {
    char* kd = smem + nb * 16384;
    char* vd = smem + 32768 + nb * 16384;
#pragma unroll
    for (int u = 0; u < 2; u++) {
      int gg = u * 512 + tid;
      int krow = gg >> 4, kcc = gg & 15;
      const bf16* kp = QKV + (size_t)(b * 2048 + kt * 64 + krow) * 4096 + 2048 +
                       kvh * 128 + ((kcc ^ (krow & 15)) * 8);
      load16(kp, kd + (u * 512 + wbase) * 16);
      int vrow = gg >> 3, vcc = gg & 7;
      const bf16* vp = Vt + (size_t)(b * 1024 + kvh * 128 + vrow) * 2048 + kt * 64 +
                       ((vcc ^ (vrow & 7)) * 8);
      load16(vp, vd + (u * 512 + wbase) * 16);
    }
  };

  stageKV(0, 0);

  floatx4 oacc[8] = {};
  floatx4 lacc = {};
  const int q0w = q0 + rgroup * 16;

  for (int kt = 0; kt < nkt; kt++) {
    const int cur = kt & 1;
    if (kt + 1 < nkt) {
      stageKV(kt + 1, cur ^ 1);  // prefetch next tile (dest last read at kt-1,
                                 // protected by kt-1's trailing barrier)
      asm volatile("s_waitcnt vmcnt(4)" ::: "memory");  // own tile-kt loads done
    } else {
      asm volatile("s_waitcnt vmcnt(0)" ::: "memory");
    }
    phase_barrier();  // tile kt globally visible
    const bf16* Kc = (const bf16*)(smem + cur * 16384);
    const bf16* Vc = (const bf16*)(smem + 32768 + cur * 16384);
    if (kt == nkt - 1)
      attn_step32<true>(Kc, Vc, Pw, aq, ones, oacc, lacc, kt * 64, q0w, l16, quad);
    else
      attn_step32<false>(Kc, Vc, Pw, aq, ones, oacc, lacc, kt * 64, q0w, l16, quad);
    phase_barrier();  // all waves done reading K/V[cur] before it is restaged
  }

  // epilogue: O = oacc / rowsum  (lacc has the row sum in every column)
  float rl[4];
#pragma unroll
  for (int r = 0; r < 4; r++) rl[r] = 1.0f / lacc[r];
#pragma unroll
  for (int j = 0; j < 8; j++)
#pragma unroll
    for (int r = 0; r < 4; r++) {
      int s = q0w + quad * 4 + r;
      O[(size_t)(b * 2048 + s) * 2048 + h * 128 + j * 16 + l16] =
          (bf16)(oacc[j][r] * rl[r]);
    }
}

extern "C" void kernel_launch(void* const* d_in, const int* in_sizes, int n_in,
                              void* d_out, int out_size, void* d_ws, size_t ws_size,
                              hipStream_t stream) {
  (void)in_sizes; (void)n_in; (void)out_size; (void)ws_size;
  const float* x    = (const float*)d_in[0];
  const float* cosb = (const float*)d_in[1];
  const float* sinb = (const float*)d_in[2];
  const float* Wq   = (const float*)d_in[3];
  const float* Wk   = (const float*)d_in[4];
  const float* Wv   = (const float*)d_in[5];
  const float* Wo   = (const float*)d_in[6];
  float* out = (float*)d_out;

  char* ws = (char*)d_ws;
  size_t off = 0;
  auto alloc = [&](size_t bytes) { void* p = ws + off; off += bytes; return p; };
  bf16* xb    = (bf16*)alloc(4096ull * 2048 * 2);  // 16 MB
  bf16* WqkvT = (bf16*)alloc(4096ull * 2048 * 2);  // 16 MB  [Wq^T | Wk^T | Wv^T]
  bf16* WoT   = (bf16*)alloc(2048ull * 2048 * 2);  //  8 MB
  bf16* QKV   = (bf16*)alloc(4096ull * 4096 * 2);  // 32 MB  [s][Q 2048 | K 1024 | V 1024]
  bf16* Vtb   = (bf16*)alloc(2048ull * 2048 * 2);  //  8 MB  [b][kv*128+hd][s]
  bf16* Ab    = (bf16*)alloc(4096ull * 2048 * 2);  // 16 MB

  // 0. x -> bf16
  cvt_kernel<<<8192, 256, 0, stream>>>(x, xb, 2097152);

  // 1. weight transposes (fp32 -> bf16), one launch
  wtrans_kernel<<<dim3(64, 64, 4), 256, 0, stream>>>(Wq, Wk, Wv, Wo, WqkvT, WoT);

  // 2. fused QKV projection: [4096 s] x [4096 n], 256^2 8-phase
  gemm256<bf16><<<dim3(16, 16), 512, 0, stream>>>(xb, WqkvT, QKV, 4096, 4096, 2048);

  // 3. RoPE on Q and K parts, one launch
  rope_kernel<<<24576, 256, 0, stream>>>(QKV, cosb, sinb);

  // 4. V transpose per batch: [2048 s][1024 c] -> [1024 c][2048 s]
  transpose_bf16<<<dim3(32, 64, 2), 256, 0, stream>>>(
      QKV + 3072, Vtb, 4096, 2048, 2048ll * 4096, 1024ll * 2048);

  // 5. flash attention v8: 8-wave blocks, 2 blocks/CU, bit-0 qt pairing
  flash_kernel<<<dim3(512, 1, 1), 512, 0, stream>>>(QKV, Vtb, Ab);

  // 6. output projection -> fp32 out, 256^2 8-phase
  gemm256<float><<<dim3(8, 16), 512, 0, stream>>>(Ab, WoT, out, 4096, 2048, 2048);
}

// Round 8
// 317.562 us; speedup vs baseline: 1.1917x; 1.0774x over previous
//
#include <hip/hip_runtime.h>

// B=2, S=2048, D=2048, H=16, KV=8, HD=128, N_REP=2.
// I/O: fp32. Compute: bf16 MFMA, fp32 accum.
//
// Pipeline (6 launches):
//   1. prep: cvt x->bf16  +  Wq/Wk/Wv/Wo transposes        (merged)
//   2. gemm256: QKV = xb @ WqkvT   (256x256 8-phase counted-vmcnt)
//   3. mid: RoPE on Q,K  +  V transpose -> Vt              (merged)
//   4. flash v8: 8-wave blocks, dbuf K/V, counted vmcnt(4), 2 blocks/CU
//   5. gemm256x128: out = Ab @ WoT  (256x128 tile -> 256 blocks, full GPU)

typedef __bf16 bf16;
typedef __bf16 bf16x4 __attribute__((ext_vector_type(4)));
typedef __bf16 bf16x8 __attribute__((ext_vector_type(8)));
typedef float floatx4 __attribute__((ext_vector_type(4)));

#define AS1(p) ((const __attribute__((address_space(1))) void*)(p))
#define AS3(p) ((__attribute__((address_space(3))) void*)(p))

__device__ __forceinline__ void load16(const void* g, void* l) {
  __builtin_amdgcn_global_load_lds(AS1(g), AS3(l), 16, 0, 0);
}

__device__ __forceinline__ void phase_barrier() {
  asm volatile("" ::: "memory");
  __builtin_amdgcn_sched_barrier(0);
  __builtin_amdgcn_s_barrier();
  __builtin_amdgcn_sched_barrier(0);
  asm volatile("" ::: "memory");
}

// ---------------- prep: cvt (blocks 0..8191) + 4 weight transposes ----------------
__global__ __launch_bounds__(256) void prep_kernel(
    const float* __restrict__ x, const float* __restrict__ Wq,
    const float* __restrict__ Wk, const float* __restrict__ Wv,
    const float* __restrict__ Wo, bf16* __restrict__ xb,
    bf16* __restrict__ WqkvT, bf16* __restrict__ WoT) {
  __shared__ float tile[32][33];
  const int bi = blockIdx.x;
  if (bi < 8192) {
    int i = bi * 256 + threadIdx.x;  // n4 = 2097152 = 8192*256 exactly
    float4 v = ((const float4*)x)[i];
    bf16x4 o = {(bf16)v.x, (bf16)v.y, (bf16)v.z, (bf16)v.w};
    ((bf16x4*)xb)[i] = o;
    return;
  }
  const int i2 = bi - 8192;
  const int wid = i2 >> 12;               // 0..3
  const int r0 = ((i2 >> 6) & 63) * 32;
  const int c0 = (i2 & 63) * 32;
  const float* src = wid == 0 ? Wq : wid == 1 ? Wk : wid == 2 ? Wv : Wo;
  bf16* dst = wid == 0 ? WqkvT
            : wid == 1 ? WqkvT + 2048ull * 2048
            : wid == 2 ? WqkvT + 3072ull * 2048
                       : WoT;
  const int ncols = (wid == 1 || wid == 2) ? 1024 : 2048;
  if (c0 >= ncols) return;
  const int tx = threadIdx.x & 31, ty = threadIdx.x >> 5;  // 32 x 8
#pragma unroll
  for (int i = 0; i < 4; i++) {
    int ri = ty + i * 8;
    tile[ri][tx] = src[(long)(r0 + ri) * ncols + c0 + tx];
  }
  __syncthreads();
#pragma unroll
  for (int i = 0; i < 4; i++) {
    int ci = ty + i * 8;
    dst[(long)(c0 + ci) * 2048 + r0 + tx] = (bf16)tile[tx][ci];
  }
}

// ---------------- mid: RoPE (blocks 0..24575) + V transpose ----------------
__global__ __launch_bounds__(256) void mid_kernel(
    bf16* __restrict__ QKV, const float* __restrict__ cosb,
    const float* __restrict__ sinb, bf16* __restrict__ Vtb) {
  __shared__ bf16 tile[32][33];
  const int bi = blockIdx.x;
  if (bi < 24576) {
    int idx = bi * 256 + threadIdx.x;  // 6291456 = 24576*256 exactly
    int nh, nhs, offc;
    if (idx < 4194304) { nh = 16; nhs = 4; offc = 0; }
    else { idx -= 4194304; nh = 8; nhs = 3; offc = 2048; }
    int d = idx & 63;
    int rest = idx >> 6;
    int hh = rest & (nh - 1);
    int bs = rest >> nhs;  // b*2048 + s
    int s = bs & 2047;
    size_t base = (size_t)bs * 4096 + offc + hh * 128;
    float c0 = cosb[s * 128 + d];
    float c1 = cosb[s * 128 + d + 64];
    float s0 = sinb[s * 128 + d];
    float s1 = sinb[s * 128 + d + 64];
    float x0 = (float)QKV[base + d];
    float x1 = (float)QKV[base + d + 64];
    QKV[base + d] = (bf16)(x0 * c0 - x1 * s0);
    QKV[base + d + 64] = (bf16)(x1 * c1 + x0 * s1);
    return;
  }
  // V transpose: per batch [2048 s][1024 c] -> [1024 c][2048 s]
  const int i2 = bi - 24576;          // 0..4095
  const int z = i2 >> 11;             // batch
  const int r0 = ((i2 >> 5) & 63) * 32;  // s
  const int c0 = (i2 & 31) * 32;         // col within V (0..1023)
  const bf16* in = QKV + 3072;
  const long ib = 2048ll * 4096 * z, ob = 1024ll * 2048 * z;
  const int tx = threadIdx.x & 31, ty = threadIdx.x >> 5;
#pragma unroll
  for (int i = 0; i < 4; i++) {
    int ri = ty + i * 8;
    tile[ri][tx] = in[ib + (long)(r0 + ri) * 4096 + c0 + tx];
  }
  __syncthreads();
#pragma unroll
  for (int i = 0; i < 4; i++) {
    int ci = ty + i * 8;
    Vtb[ob + (long)(c0 + ci) * 2048 + r0 + tx] = tile[tx][ci];
  }
}

// ---------------- GEMM 256x256, 8-phase: C[M,N] = A[M,K] * Bt[N,K]^T ----------------
// 512 threads = 8 waves (wm = wave>>2 in {0,1}, wn = wave&3 in {0..3}).
// Per-wave output 128x64 = acc[8][4] 16x16 frags.
// LDS per buffer (64KB): A [2 half][8 rg][2 kh][16 r][32 k bf16], B same at +32KB.
// Subtile block = 1024B; swizzle: byte ^= ((byte>>9)&1)<<5 (rows 8-15 flip 32B).
// Requires M%256==0, N%256==0, K%128==0.
template <typename CT>
__global__ __launch_bounds__(512, 2) void gemm256(
    const bf16* __restrict__ A, const bf16* __restrict__ Bt, CT* __restrict__ C,
    int M, int N, int K) {
  __shared__ __align__(1024) char smem[131072];
  const int tid = threadIdx.x;
  const int wave = tid >> 6, lane = tid & 63;
  const int quad = lane >> 4, l16 = lane & 15;
  const int wm = wave >> 2, wn = wave & 3;
  const int m0 = blockIdx.y * 256, n0 = blockIdx.x * 256;

  const int srow = (wave >> 1) * 16 + (lane >> 2);
  const int skcol = (wave & 1) * 32 + (((lane & 3) * 8) ^ ((lane & 32) ? 16 : 0));
  const int sblk = wave * 1024;

  const int qoff = (quad * 16) ^ ((l16 & 8) << 2);
  const int aoff = wm * 16384 + l16 * 64 + qoff;
  const int boff = 32768 + (wn >> 1) * 16384 + (wn & 1) * 8192 + l16 * 64 + qoff;

  auto stageA = [&](int kt, int h, int buf) {
    const bf16* g = A + (size_t)(m0 + h * 128 + srow) * K + kt * 64 + skcol;
    char* d = smem + buf * 65536 + h * 16384 + sblk;
    load16(g, d);
    load16(g + (size_t)64 * K, d + 8192);
  };
  auto stageB = [&](int kt, int h, int buf) {
    const bf16* g = Bt + (size_t)(n0 + h * 128 + srow) * K + kt * 64 + skcol;
    char* d = smem + buf * 65536 + 32768 + h * 16384 + sblk;
    load16(g, d);
    load16(g + (size_t)64 * K, d + 8192);
  };
  auto rdA = [&](int buf, int fr, int ks) {
    return *(const bf16x8*)(smem + buf * 65536 + aoff + (fr * 2 + ks) * 1024);
  };
  auto rdB = [&](int buf, int fc, int ks) {
    return *(const bf16x8*)(smem + buf * 65536 + boff + (fc * 2 + ks) * 1024);
  };

  floatx4 acc[8][4] = {};

  const int nkt = K >> 6;
  const int niter = nkt >> 1;

  stageB(0, 0, 0); stageB(0, 1, 0);
  stageA(0, 0, 0); stageA(0, 1, 0);
  stageB(1, 0, 1); stageB(1, 1, 1);
  asm volatile("s_waitcnt vmcnt(4)" ::: "memory");
  phase_barrier();

  for (int it = 0; it < niter; ++it) {
    const int T = 2 * it;
    const bool morek = (it < niter - 1);
#pragma unroll
    for (int c = 0; c < 2; ++c) {
      const int buf = c;
      const int tA = T + 1 + c;
      const int tB = T + 2 + c;
      const bool stA = (c == 0) || morek;

      bf16x8 a[4][2], b01[2][2], b23[2][2];

      // ---- phase 1 ----
#pragma unroll
      for (int fr = 0; fr < 4; ++fr)
#pragma unroll
        for (int ks = 0; ks < 2; ++ks) a[fr][ks] = rdA(buf, fr, ks);
#pragma unroll
      for (int fc = 0; fc < 2; ++fc)
#pragma unroll
        for (int ks = 0; ks < 2; ++ks) b01[fc][ks] = rdB(buf, fc, ks);
      if (stA) stageA(tA, 0, buf ^ 1);
      phase_barrier();
      __builtin_amdgcn_s_setprio(1);
#pragma unroll
      for (int ks = 0; ks < 2; ++ks)
#pragma unroll
        for (int fr = 0; fr < 4; ++fr)
#pragma unroll
          for (int fc = 0; fc < 2; ++fc)
            acc[fr][fc] = __builtin_amdgcn_mfma_f32_16x16x32_bf16(
                a[fr][ks], b01[fc][ks], acc[fr][fc], 0, 0, 0);
      __builtin_amdgcn_s_setprio(0);
      phase_barrier();

      // ---- phase 2 ----
#pragma unroll
      for (int fc = 0; fc < 2; ++fc)
#pragma unroll
        for (int ks = 0; ks < 2; ++ks) b23[fc][ks] = rdB(buf, 2 + fc, ks);
      if (stA) stageA(tA, 1, buf ^ 1);
      phase_barrier();
      __builtin_amdgcn_s_setprio(1);
#pragma unroll
      for (int ks = 0; ks < 2; ++ks)
#pragma unroll
        for (int fr = 0; fr < 4; ++fr)
#pragma unroll
          for (int fc = 0; fc < 2; ++fc)
            acc[fr][2 + fc] = __builtin_amdgcn_mfma_f32_16x16x32_bf16(
                a[fr][ks], b23[fc][ks], acc[fr][2 + fc], 0, 0, 0);
      __builtin_amdgcn_s_setprio(0);
      phase_barrier();

      // ---- phase 3 ----
#pragma unroll
      for (int fr = 0; fr < 4; ++fr)
#pragma unroll
        for (int ks = 0; ks < 2; ++ks) a[fr][ks] = rdA(buf, 4 + fr, ks);
      if (morek) stageB(tB, 0, buf);
      phase_barrier();
      __builtin_amdgcn_s_setprio(1);
#pragma unroll
      for (int ks = 0; ks < 2; ++ks)
#pragma unroll
        for (int fr = 0; fr < 4; ++fr)
#pragma unroll
          for (int fc = 0; fc < 2; ++fc)
            acc[4 + fr][2 + fc] = __builtin_amdgcn_mfma_f32_16x16x32_bf16(
                a[fr][ks], b23[fc][ks], acc[4 + fr][2 + fc], 0, 0, 0);
      __builtin_amdgcn_s_setprio(0);
      phase_barrier();

      // ---- phase 4 ----
      if (morek) stageB(tB, 1, buf);
      if (morek)
        asm volatile("s_waitcnt vmcnt(4)" ::: "memory");
      else
        asm volatile("s_waitcnt vmcnt(0)" ::: "memory");
      phase_barrier();
      __builtin_amdgcn_s_setprio(1);
#pragma unroll
      for (int ks = 0; ks < 2; ++ks)
#pragma unroll
        for (int fr = 0; fr < 4; ++fr)
#pragma unroll
          for (int fc = 0; fc < 2; ++fc)
            acc[4 + fr][fc] = __builtin_amdgcn_mfma_f32_16x16x32_bf16(
                a[fr][ks], b01[fc][ks], acc[4 + fr][fc], 0, 0, 0);
      __builtin_amdgcn_s_setprio(0);
      phase_barrier();
    }
  }

#pragma unroll
  for (int fr = 0; fr < 8; ++fr)
#pragma unroll
    for (int fc = 0; fc < 4; ++fc)
#pragma unroll
      for (int r = 0; r < 4; ++r) {
        int row = m0 + wm * 128 + fr * 16 + quad * 4 + r;
        int col = n0 + wn * 64 + fc * 16 + l16;
        C[(size_t)row * N + col] = (CT)acc[fr][fc][r];
      }
}

// ---------------- GEMM 256x128, 8-phase (out-projection, fp32 C) ----------------
// Same schedule as gemm256 at half N: 8 waves as 4M x 2N, per-wave 64x64 =
// acc[4][4]. LDS/buffer 48KB: A 2 halves @0, B 1 half @32K; dbuf = 96KB.
// Per 2-tile cycle each tile stages A 4 + B 2 loads; vmcnt(2) at P4 leaves
// only the newest B half-tile in flight. Requires M%256==0, N%128==0, K%128==0.
__global__ __launch_bounds__(512, 1) void gemm256x128(
    const bf16* __restrict__ A, const bf16* __restrict__ Bt, float* __restrict__ C,
    int M, int N, int K) {
  __shared__ __align__(1024) char smem[98304];
  const int tid = threadIdx.x;
  const int wave = tid >> 6, lane = tid & 63;
  const int quad = lane >> 4, l16 = lane & 15;
  const int wm = wave >> 1, wn = wave & 1;  // 4 x 2 wave grid, wave tile 64x64
  const int m0 = blockIdx.y * 256, n0 = blockIdx.x * 128;

  const int srow = (wave >> 1) * 16 + (lane >> 2);
  const int skcol = (wave & 1) * 32 + (((lane & 3) * 8) ^ ((lane & 32) ? 16 : 0));
  const int sblk = wave * 1024;

  const int qoff = (quad * 16) ^ ((l16 & 8) << 2);
  const int aoff = (wm >> 1) * 16384 + l16 * 64 + qoff;  // half select
  const int afrag = (wm & 1) * 4;                        // frag base within half
  const int boff = 32768 + l16 * 64 + qoff;
  const int bfrag = wn * 4;

  auto stageA = [&](int kt, int h, int buf) {
    const bf16* g = A + (size_t)(m0 + h * 128 + srow) * K + kt * 64 + skcol;
    char* d = smem + buf * 49152 + h * 16384 + sblk;
    load16(g, d);
    load16(g + (size_t)64 * K, d + 8192);
  };
  auto stageB = [&](int kt, int buf) {
    const bf16* g = Bt + (size_t)(n0 + srow) * K + kt * 64 + skcol;
    char* d = smem + buf * 49152 + 32768 + sblk;
    load16(g, d);
    load16(g + (size_t)64 * K, d + 8192);
  };
  auto rdA = [&](int buf, int fr, int ks) {
    return *(const bf16x8*)(smem + buf * 49152 + aoff + ((afrag + fr) * 2 + ks) * 1024);
  };
  auto rdB = [&](int buf, int fc, int ks) {
    return *(const bf16x8*)(smem + buf * 49152 + boff + ((bfrag + fc) * 2 + ks) * 1024);
  };

  floatx4 acc[4][4] = {};

  const int nkt = K >> 6;
  const int niter = nkt >> 1;

  // prologue: tile0 -> buf0 (B 2 + A 4), tile1 B -> buf1 (2); drain tile0
  stageB(0, 0);
  stageA(0, 0, 0); stageA(0, 1, 0);
  stageB(1, 1);
  asm volatile("s_waitcnt vmcnt(2)" ::: "memory");
  phase_barrier();

  for (int it = 0; it < niter; ++it) {
    const int T = 2 * it;
    const bool morek = (it < niter - 1);
#pragma unroll
    for (int c = 0; c < 2; ++c) {
      const int buf = c;
      const int tA = T + 1 + c;
      const int tB = T + 2 + c;
      const bool stA = (c == 0) || morek;

      bf16x8 a[2][2], b01[2][2], b23[2][2];

      // ---- phase 1: A frags 0-1 x B frags 0-1 ----
#pragma unroll
      for (int fr = 0; fr < 2; ++fr)
#pragma unroll
        for (int ks = 0; ks < 2; ++ks) a[fr][ks] = rdA(buf, fr, ks);
#pragma unroll
      for (int fc = 0; fc < 2; ++fc)
#pragma unroll
        for (int ks = 0; ks < 2; ++ks) b01[fc][ks] = rdB(buf, fc, ks);
      if (stA) stageA(tA, 0, buf ^ 1);
      phase_barrier();
      __builtin_amdgcn_s_setprio(1);
#pragma unroll
      for (int ks = 0; ks < 2; ++ks)
#pragma unroll
        for (int fr = 0; fr < 2; ++fr)
#pragma unroll
          for (int fc = 0; fc < 2; ++fc)
            acc[fr][fc] = __builtin_amdgcn_mfma_f32_16x16x32_bf16(
                a[fr][ks], b01[fc][ks], acc[fr][fc], 0, 0, 0);
      __builtin_amdgcn_s_setprio(0);
      phase_barrier();

      // ---- phase 2: A frags 0-1 x B frags 2-3 ----
#pragma unroll
      for (int fc = 0; fc < 2; ++fc)
#pragma unroll
        for (int ks = 0; ks < 2; ++ks) b23[fc][ks] = rdB(buf, 2 + fc, ks);
      if (stA) stageA(tA, 1, buf ^ 1);
      phase_barrier();
      __builtin_amdgcn_s_setprio(1);
#pragma unroll
      for (int ks = 0; ks < 2; ++ks)
#pragma unroll
        for (int fr = 0; fr < 2; ++fr)
#pragma unroll
          for (int fc = 0; fc < 2; ++fc)
            acc[fr][2 + fc] = __builtin_amdgcn_mfma_f32_16x16x32_bf16(
                a[fr][ks], b23[fc][ks], acc[fr][2 + fc], 0, 0, 0);
      __builtin_amdgcn_s_setprio(0);
      phase_barrier();

      // ---- phase 3: A frags 2-3 x B frags 2-3 ----
#pragma unroll
      for (int fr = 0; fr < 2; ++fr)
#pragma unroll
        for (int ks = 0; ks < 2; ++ks) a[fr][ks] = rdA(buf, 2 + fr, ks);
      if (morek) stageB(tB, buf);
      phase_barrier();
      __builtin_amdgcn_s_setprio(1);
#pragma unroll
      for (int ks = 0; ks < 2; ++ks)
#pragma unroll
        for (int fr = 0; fr < 2; ++fr)
#pragma unroll
          for (int fc = 0; fc < 2; ++fc)
            acc[2 + fr][2 + fc] = __builtin_amdgcn_mfma_f32_16x16x32_bf16(
                a[fr][ks], b23[fc][ks], acc[2 + fr][2 + fc], 0, 0, 0);
      __builtin_amdgcn_s_setprio(0);
      phase_barrier();

      // ---- phase 4: A frags 2-3 x B frags 0-1 ----
      if (morek)
        asm volatile("s_waitcnt vmcnt(2)" ::: "memory");
      else
        asm volatile("s_waitcnt vmcnt(0)" ::: "memory");
      phase_barrier();
      __builtin_amdgcn_s_setprio(1);
#pragma unroll
      for (int ks = 0; ks < 2; ++ks)
#pragma unroll
        for (int fr = 0; fr < 2; ++fr)
#pragma unroll
          for (int fc = 0; fc < 2; ++fc)
            acc[2 + fr][fc] = __builtin_amdgcn_mfma_f32_16x16x32_bf16(
                a[fr][ks], b01[fc][ks], acc[2 + fr][fc], 0, 0, 0);
      __builtin_amdgcn_s_setprio(0);
      phase_barrier();
    }
  }

#pragma unroll
  for (int fr = 0; fr < 4; ++fr)
#pragma unroll
    for (int fc = 0; fc < 4; ++fc)
#pragma unroll
      for (int r = 0; r < 4; ++r) {
        int row = m0 + wm * 64 + fr * 16 + quad * 4 + r;
        int col = n0 + wn * 64 + fc * 16 + l16;
        C[(size_t)row * N + col] = acc[fr][fc][r];
      }
}

// ---------------- Flash v8: 8-wave blocks, static bit-0-paired items ----------------
// (unchanged from round 7 — 80.7 us, VGPR 64, zero spill)
template <bool MASK>
__device__ __forceinline__ void attn_step32(
    const bf16* Kc, const bf16* Vc, bf16* Pw, const bf16x8 (&aq)[4],
    const bf16x8& ones, floatx4 (&oacc)[8], floatx4& lacc,
    int k0, int q0w, int l16, int quad) {
  floatx4 sacc[4] = {};
  __builtin_amdgcn_s_setprio(1);
#pragma unroll
  for (int ks = 0; ks < 4; ks++)
#pragma unroll
    for (int j = 0; j < 4; j++) {
      int row = j * 16 + l16;
      bf16x8 bk = *(const bf16x8*)(Kc + row * 128 + (((ks * 4 + quad) ^ (row & 15)) * 8));
      sacc[j] = __builtin_amdgcn_mfma_f32_16x16x32_bf16(aq[ks], bk, sacc[j], 0, 0, 0);
    }
  __builtin_amdgcn_s_setprio(0);
  const float C = 0.12752188659023044f;  // (1/sqrt(128)) * log2(e)
#pragma unroll
  for (int r = 0; r < 4; r++) {
    int row = quad * 4 + r;
#pragma unroll
    for (int j = 0; j < 4; j++) {
      float p = exp2f(sacc[j][r] * C);
      if (MASK) {
        int key = k0 + j * 16 + l16;
        if (key > q0w + row) p = 0.f;
      }
      int col = j * 16 + l16;
      Pw[row * 64 + (((col >> 3) ^ (row & 7)) * 8) + (col & 7)] = (bf16)p;
    }
  }
  __builtin_amdgcn_s_setprio(1);
#pragma unroll
  for (int ks = 0; ks < 2; ks++) {
    bf16x8 ap = *(const bf16x8*)(Pw + l16 * 64 + (((ks * 4 + quad) ^ (l16 & 7)) * 8));
    lacc = __builtin_amdgcn_mfma_f32_16x16x32_bf16(ap, ones, lacc, 0, 0, 0);
#pragma unroll
    for (int j = 0; j < 8; j++) {
      int vr = j * 16 + l16;
      bf16x8 bv = *(const bf16x8*)(Vc + vr * 64 + (((ks * 4 + quad) ^ (vr & 7)) * 8));
      oacc[j] = __builtin_amdgcn_mfma_f32_16x16x32_bf16(ap, bv, oacc[j], 0, 0, 0);
    }
  }
  __builtin_amdgcn_s_setprio(0);
}

__global__ __launch_bounds__(512, 4) void flash_kernel(
    const bf16* __restrict__ QKV, const bf16* __restrict__ Vt, bf16* __restrict__ O) {
  __shared__ __align__(1024) char smem[81920];
  const int tid = threadIdx.x;
  const int wave = tid >> 6, lane = tid & 63, quad = lane >> 4, l16 = lane & 15;
  const int wbase = tid & ~63;
  const int hloc = wave & 1, rgroup = wave >> 1;
  bf16* Pw = (bf16*)(smem + 65536) + wave * 1024;
  bf16x8 ones;
#pragma unroll
  for (int e = 0; e < 8; e++) ones[e] = (bf16)1.0f;

  const int w = blockIdx.x;
  const int side = w & 1, kvh = (w >> 1) & 7, b = (w >> 4) & 1, g = w >> 5;
  const int qt = side ? 31 - g : g;
  const int h = kvh * 2 + hloc;
  const int q0 = qt * 64;
  const int nkt = qt + 1;

#pragma unroll
  for (int u = 0; u < 4; u++) {
    int gg = u * 512 + tid;
    int row = gg >> 4, cc = gg & 15;
    const bf16* gp = QKV + (size_t)(b * 2048 + q0 + (row & 63)) * 4096 +
                     (kvh * 2 + (row >> 6)) * 128 + ((cc ^ (row & 15)) * 8);
    load16(gp, smem + (u * 512 + wbase) * 16);
  }
  asm volatile("s_waitcnt vmcnt(0)" ::: "memory");
  phase_barrier();
  bf16x8 aq[4];
  {
    int qr = hloc * 64 + rgroup * 16 + l16;
#pragma unroll
    for (int ks = 0; ks < 4; ks++)
      aq[ks] = *(const bf16x8*)((const bf16*)smem + qr * 128 +
                                (((ks * 4 + quad) ^ (qr & 15)) * 8));
  }
  __syncthreads();

  auto stageKV = [&](int kt, int nb) {
    char* kd = smem + nb * 16384;
    char* vd = smem + 32768 + nb * 16384;
#pragma unroll
    for (int u = 0; u < 2; u++) {
      int gg = u * 512 + tid;
      int krow = gg >> 4, kcc = gg & 15;
      const bf16* kp = QKV + (size_t)(b * 2048 + kt * 64 + krow) * 4096 + 2048 +
                       kvh * 128 + ((kcc ^ (krow & 15)) * 8);
      load16(kp, kd + (u * 512 + wbase) * 16);
      int vrow = gg >> 3, vcc = gg & 7;
      const bf16* vp = Vt + (size_t)(b * 1024 + kvh * 128 + vrow) * 2048 + kt * 64 +
                       ((vcc ^ (vrow & 7)) * 8);
      load16(vp, vd + (u * 512 + wbase) * 16);
    }
  };

  stageKV(0, 0);

  floatx4 oacc[8] = {};
  floatx4 lacc = {};
  const int q0w = q0 + rgroup * 16;

  for (int kt = 0; kt < nkt; kt++) {
    const int cur = kt & 1;
    if (kt + 1 < nkt) {
      stageKV(kt + 1, cur ^ 1);
      asm volatile("s_waitcnt vmcnt(4)" ::: "memory");
    } else {
      asm volatile("s_waitcnt vmcnt(0)" ::: "memory");
    }
    phase_barrier();
    const bf16* Kc = (const bf16*)(smem + cur * 16384);
    const bf16* Vc = (const bf16*)(smem + 32768 + cur * 16384);
    if (kt == nkt - 1)
      attn_step32<true>(Kc, Vc, Pw, aq, ones, oacc, lacc, kt * 64, q0w, l16, quad);
    else
      attn_step32<false>(Kc, Vc, Pw, aq, ones, oacc, lacc, kt * 64, q0w, l16, quad);
    phase_barrier();
  }

  float rl[4];
#pragma unroll
  for (int r = 0; r < 4; r++) rl[r] = 1.0f / lacc[r];
#pragma unroll
  for (int j = 0; j < 8; j++)
#pragma unroll
    for (int r = 0; r < 4; r++) {
      int s = q0w + quad * 4 + r;
      O[(size_t)(b * 2048 + s) * 2048 + h * 128 + j * 16 + l16] =
          (bf16)(oacc[j][r] * rl[r]);
    }
}

extern "C" void kernel_launch(void* const* d_in, const int* in_sizes, int n_in,
                              void* d_out, int out_size, void* d_ws, size_t ws_size,
                              hipStream_t stream) {
  (void)in_sizes; (void)n_in; (void)out_size; (void)ws_size;
  const float* x    = (const float*)d_in[0];
  const float* cosb = (const float*)d_in[1];
  const float* sinb = (const float*)d_in[2];
  const float* Wq   = (const float*)d_in[3];
  const float* Wk   = (const float*)d_in[4];
  const float* Wv   = (const float*)d_in[5];
  const float* Wo   = (const float*)d_in[6];
  float* out = (float*)d_out;

  char* ws = (char*)d_ws;
  size_t off = 0;
  auto alloc = [&](size_t bytes) { void* p = ws + off; off += bytes; return p; };
  bf16* xb    = (bf16*)alloc(4096ull * 2048 * 2);  // 16 MB
  bf16* WqkvT = (bf16*)alloc(4096ull * 2048 * 2);  // 16 MB  [Wq^T | Wk^T | Wv^T]
  bf16* WoT   = (bf16*)alloc(2048ull * 2048 * 2);  //  8 MB
  bf16* QKV   = (bf16*)alloc(4096ull * 4096 * 2);  // 32 MB  [s][Q 2048 | K 1024 | V 1024]
  bf16* Vtb   = (bf16*)alloc(2048ull * 2048 * 2);  //  8 MB  [b][kv*128+hd][s]
  bf16* Ab    = (bf16*)alloc(4096ull * 2048 * 2);  // 16 MB

  // 1. cvt + weight transposes (merged)
  prep_kernel<<<8192 + 16384, 256, 0, stream>>>(x, Wq, Wk, Wv, Wo, xb, WqkvT, WoT);

  // 2. fused QKV projection: [4096 s] x [4096 n], 256^2 8-phase
  gemm256<bf16><<<dim3(16, 16), 512, 0, stream>>>(xb, WqkvT, QKV, 4096, 4096, 2048);

  // 3. RoPE + V transpose (merged)
  mid_kernel<<<24576 + 4096, 256, 0, stream>>>(QKV, cosb, sinb, Vtb);

  // 4. flash attention v8: 8-wave blocks, 2 blocks/CU, bit-0 qt pairing
  flash_kernel<<<dim3(512, 1, 1), 512, 0, stream>>>(QKV, Vtb, Ab);

  // 5. output projection: 256x128 tile -> 256 blocks (full GPU)
  gemm256x128<<<dim3(16, 16), 512, 0, stream>>>(Ab, WoT, out, 4096, 2048, 2048);
}

// Round 9
// 298.926 us; speedup vs baseline: 1.2659x; 1.0623x over previous
//
#include <hip/hip_runtime.h>

// B=2, S=2048, D=2048, H=16, KV=8, HD=128, N_REP=2.
// I/O: fp32. Compute: bf16 MFMA, fp32 accum.
//
// Pipeline (5 launches):
//   1. prep: cvt x->bf16  +  Wq/Wk/Wv/Wo transposes        (merged)
//   2. gemm256: QKV = xb @ WqkvT   (256x256 8-phase counted-vmcnt)
//   3. mid: RoPE on Q,K  +  V transpose -> Vt              (merged)
//   4. flash v9: v8 body + CU-balanced qt map (co-resident blocks at strides
//      +8/+16/+256 all get nkt sums of exactly 33)
//   5. gemm256x128: out = Ab @ WoT  (256x128 tile -> 256 blocks, full GPU)

typedef __bf16 bf16;
typedef __bf16 bf16x4 __attribute__((ext_vector_type(4)));
typedef __bf16 bf16x8 __attribute__((ext_vector_type(8)));
typedef float floatx4 __attribute__((ext_vector_type(4)));

#define AS1(p) ((const __attribute__((address_space(1))) void*)(p))
#define AS3(p) ((__attribute__((address_space(3))) void*)(p))

__device__ __forceinline__ void load16(const void* g, void* l) {
  __builtin_amdgcn_global_load_lds(AS1(g), AS3(l), 16, 0, 0);
}

__device__ __forceinline__ void phase_barrier() {
  asm volatile("" ::: "memory");
  __builtin_amdgcn_sched_barrier(0);
  __builtin_amdgcn_s_barrier();
  __builtin_amdgcn_sched_barrier(0);
  asm volatile("" ::: "memory");
}

// ---------------- prep: cvt (blocks 0..8191) + 4 weight transposes ----------------
__global__ __launch_bounds__(256) void prep_kernel(
    const float* __restrict__ x, const float* __restrict__ Wq,
    const float* __restrict__ Wk, const float* __restrict__ Wv,
    const float* __restrict__ Wo, bf16* __restrict__ xb,
    bf16* __restrict__ WqkvT, bf16* __restrict__ WoT) {
  __shared__ float tile[32][33];
  const int bi = blockIdx.x;
  if (bi < 8192) {
    int i = bi * 256 + threadIdx.x;  // n4 = 2097152 = 8192*256 exactly
    float4 v = ((const float4*)x)[i];
    bf16x4 o = {(bf16)v.x, (bf16)v.y, (bf16)v.z, (bf16)v.w};
    ((bf16x4*)xb)[i] = o;
    return;
  }
  const int i2 = bi - 8192;
  const int wid = i2 >> 12;               // 0..3
  const int r0 = ((i2 >> 6) & 63) * 32;
  const int c0 = (i2 & 63) * 32;
  const float* src = wid == 0 ? Wq : wid == 1 ? Wk : wid == 2 ? Wv : Wo;
  bf16* dst = wid == 0 ? WqkvT
            : wid == 1 ? WqkvT + 2048ull * 2048
            : wid == 2 ? WqkvT + 3072ull * 2048
                       : WoT;
  const int ncols = (wid == 1 || wid == 2) ? 1024 : 2048;
  if (c0 >= ncols) return;
  const int tx = threadIdx.x & 31, ty = threadIdx.x >> 5;  // 32 x 8
#pragma unroll
  for (int i = 0; i < 4; i++) {
    int ri = ty + i * 8;
    tile[ri][tx] = src[(long)(r0 + ri) * ncols + c0 + tx];
  }
  __syncthreads();
#pragma unroll
  for (int i = 0; i < 4; i++) {
    int ci = ty + i * 8;
    dst[(long)(c0 + ci) * 2048 + r0 + tx] = (bf16)tile[tx][ci];
  }
}

// ---------------- mid: RoPE (blocks 0..24575) + V transpose ----------------
__global__ __launch_bounds__(256) void mid_kernel(
    bf16* __restrict__ QKV, const float* __restrict__ cosb,
    const float* __restrict__ sinb, bf16* __restrict__ Vtb) {
  __shared__ bf16 tile[32][33];
  const int bi = blockIdx.x;
  if (bi < 24576) {
    int idx = bi * 256 + threadIdx.x;  // 6291456 = 24576*256 exactly
    int nh, nhs, offc;
    if (idx < 4194304) { nh = 16; nhs = 4; offc = 0; }
    else { idx -= 4194304; nh = 8; nhs = 3; offc = 2048; }
    int d = idx & 63;
    int rest = idx >> 6;
    int hh = rest & (nh - 1);
    int bs = rest >> nhs;  // b*2048 + s
    int s = bs & 2047;
    size_t base = (size_t)bs * 4096 + offc + hh * 128;
    float c0 = cosb[s * 128 + d];
    float c1 = cosb[s * 128 + d + 64];
    float s0 = sinb[s * 128 + d];
    float s1 = sinb[s * 128 + d + 64];
    float x0 = (float)QKV[base + d];
    float x1 = (float)QKV[base + d + 64];
    QKV[base + d] = (bf16)(x0 * c0 - x1 * s0);
    QKV[base + d + 64] = (bf16)(x1 * c1 + x0 * s1);
    return;
  }
  // V transpose: per batch [2048 s][1024 c] -> [1024 c][2048 s]
  const int i2 = bi - 24576;          // 0..4095
  const int z = i2 >> 11;             // batch
  const int r0 = ((i2 >> 5) & 63) * 32;  // s
  const int c0 = (i2 & 31) * 32;         // col within V (0..1023)
  const bf16* in = QKV + 3072;
  const long ib = 2048ll * 4096 * z, ob = 1024ll * 2048 * z;
  const int tx = threadIdx.x & 31, ty = threadIdx.x >> 5;
#pragma unroll
  for (int i = 0; i < 4; i++) {
    int ri = ty + i * 8;
    tile[ri][tx] = in[ib + (long)(r0 + ri) * 4096 + c0 + tx];
  }
  __syncthreads();
#pragma unroll
  for (int i = 0; i < 4; i++) {
    int ci = ty + i * 8;
    Vtb[ob + (long)(c0 + ci) * 2048 + r0 + tx] = tile[tx][ci];
  }
}

// ---------------- GEMM 256x256, 8-phase: C[M,N] = A[M,K] * Bt[N,K]^T ----------------
// 512 threads = 8 waves (wm = wave>>2 in {0,1}, wn = wave&3 in {0..3}).
// Per-wave output 128x64 = acc[8][4] 16x16 frags.
// LDS per buffer (64KB): A [2 half][8 rg][2 kh][16 r][32 k bf16], B same at +32KB.
// Subtile block = 1024B; swizzle: byte ^= ((byte>>9)&1)<<5 (rows 8-15 flip 32B).
// Requires M%256==0, N%256==0, K%128==0.
template <typename CT>
__global__ __launch_bounds__(512, 2) void gemm256(
    const bf16* __restrict__ A, const bf16* __restrict__ Bt, CT* __restrict__ C,
    int M, int N, int K) {
  __shared__ __align__(1024) char smem[131072];
  const int tid = threadIdx.x;
  const int wave = tid >> 6, lane = tid & 63;
  const int quad = lane >> 4, l16 = lane & 15;
  const int wm = wave >> 2, wn = wave & 3;
  const int m0 = blockIdx.y * 256, n0 = blockIdx.x * 256;

  const int srow = (wave >> 1) * 16 + (lane >> 2);
  const int skcol = (wave & 1) * 32 + (((lane & 3) * 8) ^ ((lane & 32) ? 16 : 0));
  const int sblk = wave * 1024;

  const int qoff = (quad * 16) ^ ((l16 & 8) << 2);
  const int aoff = wm * 16384 + l16 * 64 + qoff;
  const int boff = 32768 + (wn >> 1) * 16384 + (wn & 1) * 8192 + l16 * 64 + qoff;

  auto stageA = [&](int kt, int h, int buf) {
    const bf16* g = A + (size_t)(m0 + h * 128 + srow) * K + kt * 64 + skcol;
    char* d = smem + buf * 65536 + h * 16384 + sblk;
    load16(g, d);
    load16(g + (size_t)64 * K, d + 8192);
  };
  auto stageB = [&](int kt, int h, int buf) {
    const bf16* g = Bt + (size_t)(n0 + h * 128 + srow) * K + kt * 64 + skcol;
    char* d = smem + buf * 65536 + 32768 + h * 16384 + sblk;
    load16(g, d);
    load16(g + (size_t)64 * K, d + 8192);
  };
  auto rdA = [&](int buf, int fr, int ks) {
    return *(const bf16x8*)(smem + buf * 65536 + aoff + (fr * 2 + ks) * 1024);
  };
  auto rdB = [&](int buf, int fc, int ks) {
    return *(const bf16x8*)(smem + buf * 65536 + boff + (fc * 2 + ks) * 1024);
  };

  floatx4 acc[8][4] = {};

  const int nkt = K >> 6;
  const int niter = nkt >> 1;

  stageB(0, 0, 0); stageB(0, 1, 0);
  stageA(0, 0, 0); stageA(0, 1, 0);
  stageB(1, 0, 1); stageB(1, 1, 1);
  asm volatile("s_waitcnt vmcnt(4)" ::: "memory");
  phase_barrier();

  for (int it = 0; it < niter; ++it) {
    const int T = 2 * it;
    const bool morek = (it < niter - 1);
#pragma unroll
    for (int c = 0; c < 2; ++c) {
      const int buf = c;
      const int tA = T + 1 + c;
      const int tB = T + 2 + c;
      const bool stA = (c == 0) || morek;

      bf16x8 a[4][2], b01[2][2], b23[2][2];

      // ---- phase 1 ----
#pragma unroll
      for (int fr = 0; fr < 4; ++fr)
#pragma unroll
        for (int ks = 0; ks < 2; ++ks) a[fr][ks] = rdA(buf, fr, ks);
#pragma unroll
      for (int fc = 0; fc < 2; ++fc)
#pragma unroll
        for (int ks = 0; ks < 2; ++ks) b01[fc][ks] = rdB(buf, fc, ks);
      if (stA) stageA(tA, 0, buf ^ 1);
      phase_barrier();
      __builtin_amdgcn_s_setprio(1);
#pragma unroll
      for (int ks = 0; ks < 2; ++ks)
#pragma unroll
        for (int fr = 0; fr < 4; ++fr)
#pragma unroll
          for (int fc = 0; fc < 2; ++fc)
            acc[fr][fc] = __builtin_amdgcn_mfma_f32_16x16x32_bf16(
                a[fr][ks], b01[fc][ks], acc[fr][fc], 0, 0, 0);
      __builtin_amdgcn_s_setprio(0);
      phase_barrier();

      // ---- phase 2 ----
#pragma unroll
      for (int fc = 0; fc < 2; ++fc)
#pragma unroll
        for (int ks = 0; ks < 2; ++ks) b23[fc][ks] = rdB(buf, 2 + fc, ks);
      if (stA) stageA(tA, 1, buf ^ 1);
      phase_barrier();
      __builtin_amdgcn_s_setprio(1);
#pragma unroll
      for (int ks = 0; ks < 2; ++ks)
#pragma unroll
        for (int fr = 0; fr < 4; ++fr)
#pragma unroll
          for (int fc = 0; fc < 2; ++fc)
            acc[fr][2 + fc] = __builtin_amdgcn_mfma_f32_16x16x32_bf16(
                a[fr][ks], b23[fc][ks], acc[fr][2 + fc], 0, 0, 0);
      __builtin_amdgcn_s_setprio(0);
      phase_barrier();

      // ---- phase 3 ----
#pragma unroll
      for (int fr = 0; fr < 4; ++fr)
#pragma unroll
        for (int ks = 0; ks < 2; ++ks) a[fr][ks] = rdA(buf, 4 + fr, ks);
      if (morek) stageB(tB, 0, buf);
      phase_barrier();
      __builtin_amdgcn_s_setprio(1);
#pragma unroll
      for (int ks = 0; ks < 2; ++ks)
#pragma unroll
        for (int fr = 0; fr < 4; ++fr)
#pragma unroll
          for (int fc = 0; fc < 2; ++fc)
            acc[4 + fr][2 + fc] = __builtin_amdgcn_mfma_f32_16x16x32_bf16(
                a[fr][ks], b23[fc][ks], acc[4 + fr][2 + fc], 0, 0, 0);
      __builtin_amdgcn_s_setprio(0);
      phase_barrier();

      // ---- phase 4 ----
      if (morek) stageB(tB, 1, buf);
      if (morek)
        asm volatile("s_waitcnt vmcnt(4)" ::: "memory");
      else
        asm volatile("s_waitcnt vmcnt(0)" ::: "memory");
      phase_barrier();
      __builtin_amdgcn_s_setprio(1);
#pragma unroll
      for (int ks = 0; ks < 2; ++ks)
#pragma unroll
        for (int fr = 0; fr < 4; ++fr)
#pragma unroll
          for (int fc = 0; fc < 2; ++fc)
            acc[4 + fr][fc] = __builtin_amdgcn_mfma_f32_16x16x32_bf16(
                a[fr][ks], b01[fc][ks], acc[4 + fr][fc], 0, 0, 0);
      __builtin_amdgcn_s_setprio(0);
      phase_barrier();
    }
  }

#pragma unroll
  for (int fr = 0; fr < 8; ++fr)
#pragma unroll
    for (int fc = 0; fc < 4; ++fc)
#pragma unroll
      for (int r = 0; r < 4; ++r) {
        int row = m0 + wm * 128 + fr * 16 + quad * 4 + r;
        int col = n0 + wn * 64 + fc * 16 + l16;
        C[(size_t)row * N + col] = (CT)acc[fr][fc][r];
      }
}

// ---------------- GEMM 256x128, 8-phase (out-projection, fp32 C) ----------------
// Same schedule as gemm256 at half N: 8 waves as 4M x 2N, per-wave 64x64 =
// acc[4][4]. LDS/buffer 48KB: A 2 halves @0, B 1 half @32K; dbuf = 96KB.
// Per 2-tile cycle each tile stages A 4 + B 2 loads; vmcnt(2) at P4 leaves
// only the newest B half-tile in flight. Requires M%256==0, N%128==0, K%128==0.
__global__ __launch_bounds__(512, 1) void gemm256x128(
    const bf16* __restrict__ A, const bf16* __restrict__ Bt, float* __restrict__ C,
    int M, int N, int K) {
  __shared__ __align__(1024) char smem[98304];
  const int tid = threadIdx.x;
  const int wave = tid >> 6, lane = tid & 63;
  const int quad = lane >> 4, l16 = lane & 15;
  const int wm = wave >> 1, wn = wave & 1;  // 4 x 2 wave grid, wave tile 64x64
  const int m0 = blockIdx.y * 256, n0 = blockIdx.x * 128;

  const int srow = (wave >> 1) * 16 + (lane >> 2);
  const int skcol = (wave & 1) * 32 + (((lane & 3) * 8) ^ ((lane & 32) ? 16 : 0));
  const int sblk = wave * 1024;

  const int qoff = (quad * 16) ^ ((l16 & 8) << 2);
  const int aoff = (wm >> 1) * 16384 + l16 * 64 + qoff;  // half select
  const int afrag = (wm & 1) * 4;                        // frag base within half
  const int boff = 32768 + l16 * 64 + qoff;
  const int bfrag = wn * 4;

  auto stageA = [&](int kt, int h, int buf) {
    const bf16* g = A + (size_t)(m0 + h * 128 + srow) * K + kt * 64 + skcol;
    char* d = smem + buf * 49152 + h * 16384 + sblk;
    load16(g, d);
    load16(g + (size_t)64 * K, d + 8192);
  };
  auto stageB = [&](int kt, int buf) {
    const bf16* g = Bt + (size_t)(n0 + srow) * K + kt * 64 + skcol;
    char* d = smem + buf * 49152 + 32768 + sblk;
    load16(g, d);
    load16(g + (size_t)64 * K, d + 8192);
  };
  auto rdA = [&](int buf, int fr, int ks) {
    return *(const bf16x8*)(smem + buf * 49152 + aoff + ((afrag + fr) * 2 + ks) * 1024);
  };
  auto rdB = [&](int buf, int fc, int ks) {
    return *(const bf16x8*)(smem + buf * 49152 + boff + ((bfrag + fc) * 2 + ks) * 1024);
  };

  floatx4 acc[4][4] = {};

  const int nkt = K >> 6;
  const int niter = nkt >> 1;

  // prologue: tile0 -> buf0 (B 2 + A 4), tile1 B -> buf1 (2); drain tile0
  stageB(0, 0);
  stageA(0, 0, 0); stageA(0, 1, 0);
  stageB(1, 1);
  asm volatile("s_waitcnt vmcnt(2)" ::: "memory");
  phase_barrier();

  for (int it = 0; it < niter; ++it) {
    const int T = 2 * it;
    const bool morek = (it < niter - 1);
#pragma unroll
    for (int c = 0; c < 2; ++c) {
      const int buf = c;
      const int tA = T + 1 + c;
      const int tB = T + 2 + c;
      const bool stA = (c == 0) || morek;

      bf16x8 a[2][2], b01[2][2], b23[2][2];

      // ---- phase 1: A frags 0-1 x B frags 0-1 ----
#pragma unroll
      for (int fr = 0; fr < 2; ++fr)
#pragma unroll
        for (int ks = 0; ks < 2; ++ks) a[fr][ks] = rdA(buf, fr, ks);
#pragma unroll
      for (int fc = 0; fc < 2; ++fc)
#pragma unroll
        for (int ks = 0; ks < 2; ++ks) b01[fc][ks] = rdB(buf, fc, ks);
      if (stA) stageA(tA, 0, buf ^ 1);
      phase_barrier();
      __builtin_amdgcn_s_setprio(1);
#pragma unroll
      for (int ks = 0; ks < 2; ++ks)
#pragma unroll
        for (int fr = 0; fr < 2; ++fr)
#pragma unroll
          for (int fc = 0; fc < 2; ++fc)
            acc[fr][fc] = __builtin_amdgcn_mfma_f32_16x16x32_bf16(
                a[fr][ks], b01[fc][ks], acc[fr][fc], 0, 0, 0);
      __builtin_amdgcn_s_setprio(0);
      phase_barrier();

      // ---- phase 2: A frags 0-1 x B frags 2-3 ----
#pragma unroll
      for (int fc = 0; fc < 2; ++fc)
#pragma unroll
        for (int ks = 0; ks < 2; ++ks) b23[fc][ks] = rdB(buf, 2 + fc, ks);
      if (stA) stageA(tA, 1, buf ^ 1);
      phase_barrier();
      __builtin_amdgcn_s_setprio(1);
#pragma unroll
      for (int ks = 0; ks < 2; ++ks)
#pragma unroll
        for (int fr = 0; fr < 2; ++fr)
#pragma unroll
          for (int fc = 0; fc < 2; ++fc)
            acc[fr][2 + fc] = __builtin_amdgcn_mfma_f32_16x16x32_bf16(
                a[fr][ks], b23[fc][ks], acc[fr][2 + fc], 0, 0, 0);
      __builtin_amdgcn_s_setprio(0);
      phase_barrier();

      // ---- phase 3: A frags 2-3 x B frags 2-3 ----
#pragma unroll
      for (int fr = 0; fr < 2; ++fr)
#pragma unroll
        for (int ks = 0; ks < 2; ++ks) a[fr][ks] = rdA(buf, 2 + fr, ks);
      if (morek) stageB(tB, buf);
      phase_barrier();
      __builtin_amdgcn_s_setprio(1);
#pragma unroll
      for (int ks = 0; ks < 2; ++ks)
#pragma unroll
        for (int fr = 0; fr < 2; ++fr)
#pragma unroll
          for (int fc = 0; fc < 2; ++fc)
            acc[2 + fr][2 + fc] = __builtin_amdgcn_mfma_f32_16x16x32_bf16(
                a[fr][ks], b23[fc][ks], acc[2 + fr][2 + fc], 0, 0, 0);
      __builtin_amdgcn_s_setprio(0);
      phase_barrier();

      // ---- phase 4: A frags 2-3 x B frags 0-1 ----
      if (morek)
        asm volatile("s_waitcnt vmcnt(2)" ::: "memory");
      else
        asm volatile("s_waitcnt vmcnt(0)" ::: "memory");
      phase_barrier();
      __builtin_amdgcn_s_setprio(1);
#pragma unroll
      for (int ks = 0; ks < 2; ++ks)
#pragma unroll
        for (int fr = 0; fr < 2; ++fr)
#pragma unroll
          for (int fc = 0; fc < 2; ++fc)
            acc[2 + fr][fc] = __builtin_amdgcn_mfma_f32_16x16x32_bf16(
                a[fr][ks], b01[fc][ks], acc[2 + fr][fc], 0, 0, 0);
      __builtin_amdgcn_s_setprio(0);
      phase_barrier();
    }
  }

#pragma unroll
  for (int fr = 0; fr < 4; ++fr)
#pragma unroll
    for (int fc = 0; fc < 4; ++fc)
#pragma unroll
      for (int r = 0; r < 4; ++r) {
        int row = m0 + wm * 64 + fr * 16 + quad * 4 + r;
        int col = n0 + wn * 64 + fc * 16 + l16;
        C[(size_t)row * N + col] = acc[fr][fc][r];
      }
}

// ---------------- Flash v9: v8 body + CU-balanced qt map ----------------
// w = blockIdx.x in [0,512): side = w&1, kvh = (w>>1)&7, b = (w>>4)&1, g = w>>5.
// p = g<8 ? 2g+side : 31-2(g-8)-side   (p(g^8) = 31-p)
// qt = ((kvh>>2)^b) ? 31-p : p
// => any co-resident pair differing in bit 3 (kvh), bit 4 (b) or bit 8 (g)
//    has nkt sum exactly 33 -> every CU gets equal work under XCD round-robin
//    with co-CU strides +8, +16, or +256. Coverage per (b,kvh) bijective.
// Block = 512 threads (8 waves): hloc = wave&1, rgroup = wave>>1;
// head h = 2*kvh + hloc, q-rows [qt*64 + rgroup*16, +16). K-tile = 64, nkt = qt+1.
// LDS (80 KB -> 2 blocks/CU = 16 waves/CU):
//      K0/K1 [64 key][128 hd] swz&15   16 KB @ 0, 16K   (K0+K1 = Q staging)
//      V0/V1 [128 hd][64 key] swz&7    16 KB @ 32K, 48K
//      P [wave][16 q][64 k] swz&7       2 KB/wave x 8 @ 64K
// dbuf K/V, counted vmcnt(4), 2 fenced barriers/tile, 64 VGPR, zero spill.

template <bool MASK>
__device__ __forceinline__ void attn_step32(
    const bf16* Kc, const bf16* Vc, bf16* Pw, const bf16x8 (&aq)[4],
    const bf16x8& ones, floatx4 (&oacc)[8], floatx4& lacc,
    int k0, int q0w, int l16, int quad) {
  floatx4 sacc[4] = {};
  __builtin_amdgcn_s_setprio(1);
#pragma unroll
  for (int ks = 0; ks < 4; ks++)
#pragma unroll
    for (int j = 0; j < 4; j++) {
      int row = j * 16 + l16;
      bf16x8 bk = *(const bf16x8*)(Kc + row * 128 + (((ks * 4 + quad) ^ (row & 15)) * 8));
      sacc[j] = __builtin_amdgcn_mfma_f32_16x16x32_bf16(aq[ks], bk, sacc[j], 0, 0, 0);
    }
  __builtin_amdgcn_s_setprio(0);
  const float C = 0.12752188659023044f;  // (1/sqrt(128)) * log2(e)
#pragma unroll
  for (int r = 0; r < 4; r++) {
    int row = quad * 4 + r;
#pragma unroll
    for (int j = 0; j < 4; j++) {
      float p = exp2f(sacc[j][r] * C);
      if (MASK) {
        int key = k0 + j * 16 + l16;
        if (key > q0w + row) p = 0.f;
      }
      int col = j * 16 + l16;
      Pw[row * 64 + (((col >> 3) ^ (row & 7)) * 8) + (col & 7)] = (bf16)p;
    }
  }
  __builtin_amdgcn_s_setprio(1);
#pragma unroll
  for (int ks = 0; ks < 2; ks++) {
    bf16x8 ap = *(const bf16x8*)(Pw + l16 * 64 + (((ks * 4 + quad) ^ (l16 & 7)) * 8));
    lacc = __builtin_amdgcn_mfma_f32_16x16x32_bf16(ap, ones, lacc, 0, 0, 0);
#pragma unroll
    for (int j = 0; j < 8; j++) {
      int vr = j * 16 + l16;
      bf16x8 bv = *(const bf16x8*)(Vc + vr * 64 + (((ks * 4 + quad) ^ (vr & 7)) * 8));
      oacc[j] = __builtin_amdgcn_mfma_f32_16x16x32_bf16(ap, bv, oacc[j], 0, 0, 0);
    }
  }
  __builtin_amdgcn_s_setprio(0);
}

__global__ __launch_bounds__(512, 4) void flash_kernel(
    const bf16* __restrict__ QKV, const bf16* __restrict__ Vt, bf16* __restrict__ O) {
  __shared__ __align__(1024) char smem[81920];
  const int tid = threadIdx.x;
  const int wave = tid >> 6, lane = tid & 63, quad = lane >> 4, l16 = lane & 15;
  const int wbase = tid & ~63;
  const int hloc = wave & 1, rgroup = wave >> 1;
  bf16* Pw = (bf16*)(smem + 65536) + wave * 1024;
  bf16x8 ones;
#pragma unroll
  for (int e = 0; e < 8; e++) ones[e] = (bf16)1.0f;

  const int w = blockIdx.x;
  const int side = w & 1, kvh = (w >> 1) & 7, b = (w >> 4) & 1, g = w >> 5;
  const int p = (g < 8) ? (2 * g + side) : (31 - 2 * (g - 8) - side);
  const int qt = (((kvh >> 2) ^ b) & 1) ? 31 - p : p;
  const int h = kvh * 2 + hloc;
  const int q0 = qt * 64;
  const int nkt = qt + 1;

#pragma unroll
  for (int u = 0; u < 4; u++) {
    int gg = u * 512 + tid;
    int row = gg >> 4, cc = gg & 15;
    const bf16* gp = QKV + (size_t)(b * 2048 + q0 + (row & 63)) * 4096 +
                     (kvh * 2 + (row >> 6)) * 128 + ((cc ^ (row & 15)) * 8);
    load16(gp, smem + (u * 512 + wbase) * 16);
  }
  asm volatile("s_waitcnt vmcnt(0)" ::: "memory");
  phase_barrier();
  bf16x8 aq[4];
  {
    int qr = hloc * 64 + rgroup * 16 + l16;
#pragma unroll
    for (int ks = 0; ks < 4; ks++)
      aq[ks] = *(const bf16x8*)((const bf16*)smem + qr * 128 +
                                (((ks * 4 + quad) ^ (qr & 15)) * 8));
  }
  __syncthreads();

  auto stageKV = [&](int kt, int nb) {
    char* kd = smem + nb * 16384;
    char* vd = smem + 32768 + nb * 16384;
#pragma unroll
    for (int u = 0; u < 2; u++) {
      int gg = u * 512 + tid;
      int krow = gg >> 4, kcc = gg & 15;
      const bf16* kp = QKV + (size_t)(b * 2048 + kt * 64 + krow) * 4096 + 2048 +
                       kvh * 128 + ((kcc ^ (krow & 15)) * 8);
      load16(kp, kd + (u * 512 + wbase) * 16);
      int vrow = gg >> 3, vcc = gg & 7;
      const bf16* vp = Vt + (size_t)(b * 1024 + kvh * 128 + vrow) * 2048 + kt * 64 +
                       ((vcc ^ (vrow & 7)) * 8);
      load16(vp, vd + (u * 512 + wbase) * 16);
    }
  };

  stageKV(0, 0);

  floatx4 oacc[8] = {};
  floatx4 lacc = {};
  const int q0w = q0 + rgroup * 16;

  for (int kt = 0; kt < nkt; kt++) {
    const int cur = kt & 1;
    if (kt + 1 < nkt) {
      stageKV(kt + 1, cur ^ 1);
      asm volatile("s_waitcnt vmcnt(4)" ::: "memory");
    } else {
      asm volatile("s_waitcnt vmcnt(0)" ::: "memory");
    }
    phase_barrier();
    const bf16* Kc = (const bf16*)(smem + cur * 16384);
    const bf16* Vc = (const bf16*)(smem + 32768 + cur * 16384);
    if (kt == nkt - 1)
      attn_step32<true>(Kc, Vc, Pw, aq, ones, oacc, lacc, kt * 64, q0w, l16, quad);
    else
      attn_step32<false>(Kc, Vc, Pw, aq, ones, oacc, lacc, kt * 64, q0w, l16, quad);
    phase_barrier();
  }

  float rl[4];
#pragma unroll
  for (int r = 0; r < 4; r++) rl[r] = 1.0f / lacc[r];
#pragma unroll
  for (int j = 0; j < 8; j++)
#pragma unroll
    for (int r = 0; r < 4; r++) {
      int s = q0w + quad * 4 + r;
      O[(size_t)(b * 2048 + s) * 2048 + h * 128 + j * 16 + l16] =
          (bf16)(oacc[j][r] * rl[r]);
    }
}

extern "C" void kernel_launch(void* const* d_in, const int* in_sizes, int n_in,
                              void* d_out, int out_size, void* d_ws, size_t ws_size,
                              hipStream_t stream) {
  (void)in_sizes; (void)n_in; (void)out_size; (void)ws_size;
  const float* x    = (const float*)d_in[0];
  const float* cosb = (const float*)d_in[1];
  const float* sinb = (const float*)d_in[2];
  const float* Wq   = (const float*)d_in[3];
  const float* Wk   = (const float*)d_in[4];
  const float* Wv   = (const float*)d_in[5];
  const float* Wo   = (const float*)d_in[6];
  float* out = (float*)d_out;

  char* ws = (char*)d_ws;
  size_t off = 0;
  auto alloc = [&](size_t bytes) { void* p = ws + off; off += bytes; return p; };
  bf16* xb    = (bf16*)alloc(4096ull * 2048 * 2);  // 16 MB
  bf16* WqkvT = (bf16*)alloc(4096ull * 2048 * 2);  // 16 MB  [Wq^T | Wk^T | Wv^T]
  bf16* WoT   = (bf16*)alloc(2048ull * 2048 * 2);  //  8 MB
  bf16* QKV   = (bf16*)alloc(4096ull * 4096 * 2);  // 32 MB  [s][Q 2048 | K 1024 | V 1024]
  bf16* Vtb   = (bf16*)alloc(2048ull * 2048 * 2);  //  8 MB  [b][kv*128+hd][s]
  bf16* Ab    = (bf16*)alloc(4096ull * 2048 * 2);  // 16 MB

  // 1. cvt + weight transposes (merged)
  prep_kernel<<<8192 + 16384, 256, 0, stream>>>(x, Wq, Wk, Wv, Wo, xb, WqkvT, WoT);

  // 2. fused QKV projection: [4096 s] x [4096 n], 256^2 8-phase
  gemm256<bf16><<<dim3(16, 16), 512, 0, stream>>>(xb, WqkvT, QKV, 4096, 4096, 2048);

  // 3. RoPE + V transpose (merged)
  mid_kernel<<<24576 + 4096, 256, 0, stream>>>(QKV, cosb, sinb, Vtb);

  // 4. flash attention v9: CU-balanced qt map
  flash_kernel<<<dim3(512, 1, 1), 512, 0, stream>>>(QKV, Vtb, Ab);

  // 5. output projection: 256x128 tile -> 256 blocks (full GPU)
  gemm256x128<<<dim3(16, 16), 512, 0, stream>>>(Ab, WoT, out, 4096, 2048, 2048);
}